// Round 7
// baseline (252.362 us; speedup 1.0000x reference)
//
#include <hip/hip_runtime.h>
#include <math.h>

// ---------------------------------------------------------------------------
// VQVAE forward. v16: conv2 ci-split for 2 blocks/CU. v15 profile: conv2 back
// on top (45.8 us) at 1 block/CU (grid 256), MfmaUtil 14.9 / occ 18.5 --
// latency-exposed. v16 splits the ci-reduction: 512 blocks (b x ohq x half),
// IDENTICAL tile/dbuf/step structure (2 steps instead of 4), each half writes
// unbiased partial sums to h2a/h2b; k_poolproj computes relu(h2a+h2b+b2)
// before pooling (one re-associated f32 add; no atomics). TLP doubles at
// constant structure -- the clean occupancy test v13 wasn't.
// ---------------------------------------------------------------------------

typedef _Float16 f16x8 __attribute__((ext_vector_type(8)));
typedef float f32x4 __attribute__((ext_vector_type(4)));

#define H1N 16777216        // elements in h1 plane; zero tail after
#define YTAIL (2048 * 128)  // zero page in Yh/Yl for OOB shifts

// ---------- prep: A-agg (0..127), W-split (128..143), cbT (144..151), misc --
__global__ __launch_bounds__(256) void k_prep(const float* __restrict__ w2,
                                              const float* __restrict__ w1,
                                              const float* __restrict__ wp,
                                              const float* __restrict__ wd,
                                              const float* __restrict__ wd1,
                                              const float* __restrict__ cb,
                                              float* __restrict__ w1t,
                                              float* __restrict__ wpT,
                                              float* __restrict__ wdT,
                                              float* __restrict__ cbT,
                                              _Float16* __restrict__ Ah,
                                              _Float16* __restrict__ Al,
                                              _Float16* __restrict__ Wh,
                                              _Float16* __restrict__ Wl,
                                              _Float16* __restrict__ h1h) {
  int bx = blockIdx.x, tid = threadIdx.x;
  if (bx < 128) {  // ---- A aggregation, block = co, lanes = ci (writes coalesced)
    __shared__ float wrow[1152];
    int co = bx;
    for (int i = tid; i < 1152; i += 256) wrow[i] = wd1[co * 1152 + i];
    __syncthreads();
    if (tid < 128) {
      int ci = tid;
      float w[9];
#pragma unroll
      for (int t = 0; t < 9; t++) w[t] = wrow[ci * 9 + t];
      float rx[3][5];
#pragma unroll
      for (int ky = 0; ky < 3; ky++) {
        float a0 = w[ky * 3 + 0], a1 = w[ky * 3 + 1], a2 = w[ky * 3 + 2];
        rx[ky][0] = a0; rx[ky][1] = a1 + a2; rx[ky][2] = a0 + a1 + a2;
        rx[ky][3] = a0 + a1; rx[ky][4] = a2;
      }
#pragma unroll
      for (int px = 0; px < 5; px++) {
        float s0 = rx[0][px], s1 = rx[1][px], s2 = rx[2][px];
        float ry[5];
        ry[0] = s0; ry[1] = s1 + s2; ry[2] = s0 + s1 + s2; ry[3] = s0 + s1; ry[4] = s2;
#pragma unroll
        for (int py = 0; py < 5; py++) {
          int pq = py * 5 + px;
          float v = ry[py];
          _Float16 h = (_Float16)v;
          int o = (pq * 128 + co) * 128 + ci;
          Ah[o] = h;
          Al[o] = (_Float16)(v - (float)h);
        }
      }
    }
    return;
  }
  if (bx < 144) {  // ---- W f16-split: 8 co per block, LDS-staged, coalesced RW
    __shared__ float wst[9216];
    int co0 = (bx - 128) * 8;
    for (int i = tid; i < 9216; i += 256) wst[i] = w2[co0 * 1152 + i];
    __syncthreads();
    for (int i = tid; i < 9216; i += 256) {
      int co = i / 1152, r = i - co * 1152;
      int tap = r >> 7, ci = r & 127;
      float v = wst[co * 1152 + ci * 9 + tap];
      _Float16 h = (_Float16)v;
      int o = (tap * 128 + co0 + co) * 128 + ci;
      Wh[o] = h;
      Wl[o] = (_Float16)(v - (float)h);
    }
    return;
  }
  if (bx < 152) {  // ---- cbT tile transpose (64 k x 64 d), padded LDS
    __shared__ float cbs[64 * 65];
    int k0 = (bx - 144) * 64;
    for (int i = tid; i < 4096; i += 256) {
      int k = i >> 6, d = i & 63;
      cbs[k * 65 + d] = cb[(k0 + k) * 64 + d];
    }
    __syncthreads();
    for (int i = tid; i < 4096; i += 256) {
      int d = i >> 6, k = i & 63;
      cbT[d * 512 + k0 + k] = cbs[k * 65 + d];
    }
    return;
  }
  // ---- misc small transposes + h1 zero tail (writes lane-contiguous)
  for (int i = tid; i < 3456; i += 256) {  // w1t[t][co] = w1[co][t]
    int co = i & 127, t = i >> 7;
    w1t[t * 128 + co] = w1[co * 27 + t];
  }
  for (int i = tid; i < 8192; i += 256) {  // wpT[k][d] = wp[d][k]
    int d = i & 63, k = i >> 6;
    wpT[k * 64 + d] = wp[d * 128 + k];
  }
  for (int i = tid; i < 8192; i += 256) {  // wdT[d][co] = wd[co][d]
    int co = i & 127, d = i >> 7;
    wdT[d * 128 + co] = wd[co * 64 + d];
  }
  if (tid < 64) h1h[H1N + tid] = (_Float16)0.f;
}

// ---------- conv1: (32,3,128,128) -> h1 f16 [g][b][oh][ow][8ci] -------------
__global__ __launch_bounds__(256) void k_conv1(const float* __restrict__ x,
                                               const float* __restrict__ w1t,
                                               const float* __restrict__ b1,
                                               _Float16* __restrict__ h1h) {
  __shared__ float E[3][9][68];
  __shared__ float O[3][9][68];
  int co_t = blockIdx.x, oh_t = blockIdx.y, b = blockIdx.z;
  int oh0 = oh_t * 4;
  int tid = threadIdx.x;
  int wv = __builtin_amdgcn_readfirstlane(tid >> 6);
  int l = tid & 63;
  int coB = co_t * 32 + wv * 8;

  for (int idx = tid; idx < 1728; idx += 256) {
    int p = idx & 63, r = idx >> 6;
    int ci = r / 9, lr = r - ci * 9;
    int ih = 2 * oh0 - 1 + lr;
    float2 v = make_float2(0.f, 0.f);
    if ((unsigned)ih < 128u)
      v = *(const float2*)&x[((b * 3 + ci) * 128 + ih) * 128 + 2 * p];
    E[ci][lr][p] = v.x;
    O[ci][lr][p + 1] = v.y;
  }
  if (tid < 27) {
    int ci = tid / 9, lr = tid - ci * 9;
    O[ci][lr][0] = 0.f;
  }
  __syncthreads();

  int ohl = l >> 4, ow0 = (l & 15) * 4;
  int oh = oh0 + ohl;
  float4 acc[8];
#pragma unroll
  for (int q = 0; q < 8; q++) {
    float bv = b1[coB + q];
    acc[q] = make_float4(bv, bv, bv, bv);
  }
#pragma unroll
  for (int ci = 0; ci < 3; ci++) {
#pragma unroll
    for (int ky = 0; ky < 3; ky++) {
      int lr = 2 * ohl + ky;
      float4 ev = *(float4*)&E[ci][lr][ow0];
      float4 od = *(float4*)&O[ci][lr][ow0];
      float o4 = O[ci][lr][ow0 + 4];
      const float* wr = w1t + (ci * 9 + ky * 3) * 128 + coB;
#pragma unroll
      for (int q = 0; q < 8; q++) {
        float wa = wr[q], wb = wr[128 + q], wc = wr[256 + q];
        acc[q].x = fmaf(wa, od.x, acc[q].x);
        acc[q].x = fmaf(wb, ev.x, acc[q].x);
        acc[q].x = fmaf(wc, od.y, acc[q].x);
        acc[q].y = fmaf(wa, od.y, acc[q].y);
        acc[q].y = fmaf(wb, ev.y, acc[q].y);
        acc[q].y = fmaf(wc, od.z, acc[q].y);
        acc[q].z = fmaf(wa, od.z, acc[q].z);
        acc[q].z = fmaf(wb, ev.z, acc[q].z);
        acc[q].z = fmaf(wc, od.w, acc[q].z);
        acc[q].w = fmaf(wa, od.w, acc[q].w);
        acc[q].w = fmaf(wb, ev.w, acc[q].w);
        acc[q].w = fmaf(wc, o4,   acc[q].w);
      }
    }
  }
  int g = coB >> 3;
  int pbase = ((g * 32 + b) * 64 + oh) * 64;
#pragma unroll
  for (int oi = 0; oi < 4; oi++) {
    f16x8 hv;
#pragma unroll
    for (int q = 0; q < 8; q++)
      hv[q] = (_Float16)fmaxf(((const float*)&acc[q])[oi], 0.f);
    *(f16x8*)&h1h[(pbase + ow0 + oi) * 8] = hv;
  }
}

// ---------- conv2: 2-term split MFMA, ci-split halves, 2 blocks/CU ----------
// grid 512 = (b(32) x ohq(8) x half(2)); block 512 = 8 waves. wave w:
// co-group (w&3), row-group rw=(w>>2). Each block reduces ci in
// [half*64, half*64+64) over 2 K-steps (identical tile/dbuf/barrier
// structure to v14) and writes UNBIASED partial sums to h2p[half];
// k_poolproj combines relu(h2a+h2b+b2). LDS chunk c = (g*9 + r)*65 +
// (ph? 33+u : u), g=ci8-group(4), r=row(9), ph=0: iw=2u-1, ph=1: iw=2u.
#define C2_CHUNKS 2340
#define C2_BUF (C2_CHUNKS * 8)   // f16 elems per buffer
#define C2_LDS (2 * C2_BUF * 2)  // bytes = 74880
#define C2_STEP 4194304          // h1 element advance per +32ci step
#define C2_HALF 8388608          // h1 element offset per ci-half (8 g-groups)

__global__ __launch_bounds__(512, 2) void k_conv2(const _Float16* __restrict__ h1h,
                                                  const _Float16* __restrict__ Wh,
                                                  const _Float16* __restrict__ Wl,
                                                  float* __restrict__ h2a,
                                                  float* __restrict__ h2b) {
  extern __shared__ _Float16 Bbuf[];
  int bx = blockIdx.x;
  int half = bx & 1;
  int bq = bx >> 1;
  int b = bq >> 3, ohq = bq & 7;
  int oh0 = ohq * 4;
  int tid = threadIdx.x;
  int w = tid >> 6, l = tid & 63;
  int cw = w & 3, rw = w >> 2;
  int ln = l & 15, quad = l >> 4;
  int coW = cw * 32;
  int kq = quad * 8;

  // ---- staging descriptors: 5 chunks/thread (last partial, tid<292) ----
  int cursrc[5];
  int adv[5];
#pragma unroll
  for (int k = 0; k < 5; k++) {
    int c = (k < 4) ? (tid + k * 512) : (2048 + tid);
    if (c < C2_CHUNKS) {
      int q = c / 65, rem = c - q * 65;
      int ph = rem >= 33;
      int u = ph ? rem - 33 : rem;
      int r = q % 9, g = q / 9;
      int iw = ph ? 2 * u : 2 * u - 1;
      int ih = 2 * oh0 - 1 + r;
      bool ok = (ih >= 0) && (iw >= 0) && (iw < 64);
      cursrc[k] = ok ? half * C2_HALF + ((g * 32 + b) * 64 + ih) * 512 + iw * 8
                     : H1N;
      adv[k] = ok ? C2_STEP : 0;
    } else {
      cursrc[k] = H1N;
      adv[k] = 0;
    }
  }

#define C2_STAGE(DST)                                                          \
  {                                                                            \
    _Pragma("unroll") for (int k = 0; k < 4; k++) {                            \
      __builtin_amdgcn_global_load_lds(                                        \
          (const __attribute__((address_space(1))) void*)(h1h + cursrc[k]),    \
          (__attribute__((address_space(3))) void*)&Bbuf[(DST) +               \
                                                         (tid + k * 512) * 8], \
          16, 0, 0);                                                           \
      cursrc[k] += adv[k];                                                     \
    }                                                                          \
    if (tid < 292) {                                                           \
      __builtin_amdgcn_global_load_lds(                                        \
          (const __attribute__((address_space(1))) void*)(h1h + cursrc[4]),    \
          (__attribute__((address_space(3))) void*)&Bbuf[(DST) +               \
                                                         (2048 + tid) * 8],    \
          16, 0, 0);                                                           \
    }                                                                          \
    cursrc[4] += adv[4];                                                       \
  }

  int curoff = 0;
  C2_STAGE(0);      // prologue: stage K-step 0 into buffer 0
  __syncthreads();  // drain + barrier

  f32x4 acc[2][4] = {};  // [cs][s]  s = (row-in-pair<<1)|col-half
  for (int step = 0; step < 2; step++) {
    int nxt = curoff ^ C2_BUF;
    if (step < 1) C2_STAGE(nxt);  // issue next K-step's loads
    const int ci0 = half * 64 + step * 32;
#pragma unroll
    for (int ky = 0; ky < 3; ky++) {
#pragma unroll
      for (int kx = 0; kx < 3; kx++) {
        int tap = ky * 3 + kx;
        const int wbase = (tap * 128 + coW + ln) * 128 + ci0 + kq;
        f16x8 Ah0 = *(const f16x8*)&Wh[wbase];
        f16x8 Al0 = *(const f16x8*)&Wl[wbase];
        f16x8 Ah1 = *(const f16x8*)&Wh[wbase + 2048];  // +16 co
        f16x8 Al1 = *(const f16x8*)&Wl[wbase + 2048];
#pragma unroll
        for (int s = 0; s < 4; s++) {
          int owl = (s & 1) * 16 + ln;
          int r = 4 * rw + 2 * (s >> 1) + ky;
          int base = (quad * 9 + r) * 65;
          int uoff = (kx == 1) ? (33 + owl) : (owl + (kx == 2));
          f16x8 Bh = *(const f16x8*)&Bbuf[curoff + (base + uoff) * 8];
          acc[0][s] = __builtin_amdgcn_mfma_f32_16x16x32_f16(Al0, Bh, acc[0][s], 0, 0, 0);
          acc[0][s] = __builtin_amdgcn_mfma_f32_16x16x32_f16(Ah0, Bh, acc[0][s], 0, 0, 0);
          acc[1][s] = __builtin_amdgcn_mfma_f32_16x16x32_f16(Al1, Bh, acc[1][s], 0, 0, 0);
          acc[1][s] = __builtin_amdgcn_mfma_f32_16x16x32_f16(Ah1, Bh, acc[1][s], 0, 0, 0);
        }
      }
    }
    __syncthreads();  // loads into nxt done; all done reading cur
    curoff = nxt;
  }
  // epilogue: unbiased partial sums to this half's buffer
  float* hp = half ? h2b : h2a;
#pragma unroll
  for (int cs = 0; cs < 2; cs++)
#pragma unroll
    for (int s = 0; s < 4; s++) {
      int oh = oh0 + 2 * rw + (s >> 1);
      int ow = (s & 1) * 16 + ln;
#pragma unroll
      for (int r = 0; r < 4; r++) {
        int co = coW + cs * 16 + quad * 4 + r;
        hp[((b * 128 + co) * 32 + oh) * 32 + ow] = acc[cs][s][r];
      }
    }
#undef C2_STAGE
}

// ---------- pool(4x4 mean of relu(h2a+h2b+b2)) + proj; grid 128 -------------
__global__ __launch_bounds__(256) void k_poolproj(const float* __restrict__ h2a,
                                                  const float* __restrict__ h2b,
                                                  const float* __restrict__ b2,
                                                  const float* __restrict__ wpT,
                                                  const float* __restrict__ pb,
                                                  float* __restrict__ z_e_out,
                                                  float* __restrict__ lossacc) {
  __shared__ float hp[128][16];
  __shared__ float Ws[128][64];
  int bx = blockIdx.x, tid = threadIdx.x;
  int b = bx >> 2, quarter = bx & 3;
  if (bx == 0 && tid == 0) lossacc[0] = 0.f;
  for (int i = tid; i < 8192; i += 256) Ws[i >> 6][i & 63] = wpT[i];
  for (int i = tid; i < 2048; i += 256) {
    int ci = i >> 4, pl = i & 15;
    int pi = quarter * 16 + pl;
    int bi = pi >> 3, bj = pi & 7;
    int off = ((b * 128 + ci) * 32 + bi * 4) * 32 + bj * 4;
    float bv = b2[ci];
    float s = 0.f;
#pragma unroll
    for (int rr = 0; rr < 4; rr++) {
      float4 ra = *(const float4*)&h2a[off + rr * 32];
      float4 rb = *(const float4*)&h2b[off + rr * 32];
      s += fmaxf(ra.x + rb.x + bv, 0.f);
      s += fmaxf(ra.y + rb.y + bv, 0.f);
      s += fmaxf(ra.z + rb.z + bv, 0.f);
      s += fmaxf(ra.w + rb.w + bv, 0.f);
    }
    hp[ci][pl] = s * 0.0625f;
  }
  __syncthreads();
  int d = tid >> 2, s0 = (tid & 3) * 4;
  float4 acc = make_float4(0.f, 0.f, 0.f, 0.f);
  for (int k = 0; k < 128; k++) {
    float a = Ws[k][d];
    float4 h = *(float4*)&hp[k][s0];
    acc.x = fmaf(a, h.x, acc.x);
    acc.y = fmaf(a, h.y, acc.y);
    acc.z = fmaf(a, h.z, acc.z);
    acc.w = fmaf(a, h.w, acc.w);
  }
  float bv = pb[d];
  float4 r4 = make_float4(acc.x + bv, acc.y + bv, acc.z + bv, acc.w + bv);
  *(float4*)&z_e_out[(b * 64 + d) * 64 + quarter * 16 + s0] = r4;
}

// ---------- VQ argmin + loss + dproj; grid 2048 x 256 (4 waves) -------------
// wave w owns codes [w*128, w*128+128), 2/lane; per-code f64 distance math is
// bit-identical to the 1-wave version (same accumulator order); reduction
// preserves smallest-index-on-tie (wave shuffle -> ascending 4-way LDS fold).
__global__ __launch_bounds__(256) void k_vqdproj(const float* __restrict__ z_e,
                                                 const float* __restrict__ cbT,
                                                 const float* __restrict__ cb,
                                                 const float* __restrict__ wdT,
                                                 const float* __restrict__ db,
                                                 float* __restrict__ idx_f,
                                                 _Float16* __restrict__ Yh,
                                                 _Float16* __restrict__ Yl,
                                                 float* __restrict__ loss_acc) {
  __shared__ float zs[64];
  __shared__ float zqv[64];
  __shared__ double wbst[4];
  __shared__ int wbi[4];
  int n = blockIdx.x, tid = threadIdx.x;
  int b = n >> 6, pi = n & 63;
  if (tid < 64) zs[tid] = z_e[(b * 64 + tid) * 64 + pi];
  if (n == 0 && tid < 64) {  // zero tail page for shifted reads in k_dec
    Yh[YTAIL + tid] = (_Float16)0.f;
    Yh[YTAIL + 64 + tid] = (_Float16)0.f;
    Yl[YTAIL + tid] = (_Float16)0.f;
    Yl[YTAIL + 64 + tid] = (_Float16)0.f;
  }
  __syncthreads();
  int w = tid >> 6, lane = tid & 63;
  double best = 1e300;
  int bi = 0;
#pragma unroll
  for (int j = 0; j < 2; j++) {
    int k = w * 128 + j * 64 + lane;
    double a0 = 0.0, a1 = 0.0, a2 = 0.0, a3 = 0.0;
#pragma unroll 4
    for (int d = 0; d < 64; d += 4) {
      double f0 = (double)zs[d] - (double)cbT[d * 512 + k];
      double f1 = (double)zs[d + 1] - (double)cbT[(d + 1) * 512 + k];
      double f2 = (double)zs[d + 2] - (double)cbT[(d + 2) * 512 + k];
      double f3 = (double)zs[d + 3] - (double)cbT[(d + 3) * 512 + k];
      a0 = fma(f0, f0, a0);
      a1 = fma(f1, f1, a1);
      a2 = fma(f2, f2, a2);
      a3 = fma(f3, f3, a3);
    }
    double acc = (a0 + a1) + (a2 + a3);
    if (acc < best) { best = acc; bi = k; }
  }
  for (int m = 1; m < 64; m <<= 1) {
    double ob = __shfl_xor(best, m, 64);
    int oi = __shfl_xor(bi, m, 64);
    if (ob < best || (ob == best && oi < bi)) { best = ob; bi = oi; }
  }
  if (lane == 0) { wbst[w] = best; wbi[w] = bi; }
  __syncthreads();
  best = wbst[0];
  bi = wbi[0];
#pragma unroll
  for (int q = 1; q < 4; q++) {
    double ob = wbst[q];
    int oi = wbi[q];
    if (ob < best || (ob == best && oi < bi)) { best = ob; bi = oi; }
  }
  if (tid < 64) {  // wave 0: loss + zq staging
    float zq_l = cb[bi * 64 + tid];
    float e = zq_l - zs[tid];
    float sq = e * e;
    for (int m = 1; m < 64; m <<= 1) sq += __shfl_xor(sq, m, 64);
    if (tid == 0) {
      idx_f[n] = (float)bi;
      atomicAdd(loss_acc, sq);
    }
    zqv[tid] = zq_l;
  }
  __syncthreads();
  if (tid < 128) {  // dproj: one co per thread
    float a = db[tid];
#pragma unroll 4
    for (int d = 0; d < 64; d++) a = fmaf(wdT[d * 128 + tid], zqv[d], a);
    float y = fmaxf(a, 0.f);
    _Float16 h = (_Float16)y;
    Yh[n * 128 + tid] = h;
    Yl[n * 128 + tid] = (_Float16)(y - (float)h);
  }
}

// ---------- dec: f16-split MFMA, G[pq][n][co] = A_pq * Yshift ----------
__global__ __launch_bounds__(256) void k_dec(const _Float16* __restrict__ Yh,
                                             const _Float16* __restrict__ Yl,
                                             const _Float16* __restrict__ Ah,
                                             const _Float16* __restrict__ Al,
                                             float* __restrict__ G) {
  int bxx = blockIdx.x;
  int pq = bxx >> 6, n_t = bxx & 63;
  int w = threadIdx.x >> 6, l = threadIdx.x & 63;
  int ln = l & 15, quad = l >> 4;
  int coW = w * 32;
  int nB = n_t * 32;
  int py = pq / 5, px = pq - py * 5;
  int dy = (py == 0) ? -1 : ((py == 4) ? 1 : 0);
  int dx = (px == 0) ? -1 : ((px == 4) ? 1 : 0);
  int src[2];
#pragma unroll
  for (int s = 0; s < 2; s++) {
    int n = nB + s * 16 + ln;
    int bb = n >> 6, s6 = n & 63;
    int sy = (s6 >> 3) + dy, sx = (s6 & 7) + dx;
    bool ok = ((unsigned)sy < 8u) && ((unsigned)sx < 8u);
    src[s] = ok ? ((bb * 64 + sy * 8 + sx) * 128) : YTAIL;
  }
  int kq = quad * 8;
  f32x4 acc[2][2] = {};
#pragma unroll 2
  for (int ci0 = 0; ci0 < 128; ci0 += 32) {
    const int wbase = (pq * 128 + coW + ln) * 128 + ci0 + kq;
    f16x8 Ah0 = *(const f16x8*)&Ah[wbase];
    f16x8 Al0 = *(const f16x8*)&Al[wbase];
    f16x8 Ah1 = *(const f16x8*)&Ah[wbase + 2048];
    f16x8 Al1 = *(const f16x8*)&Al[wbase + 2048];
    f16x8 Bh[2], Bl[2];
#pragma unroll
    for (int s = 0; s < 2; s++) {
      Bh[s] = *(const f16x8*)&Yh[src[s] + ci0 + kq];
      Bl[s] = *(const f16x8*)&Yl[src[s] + ci0 + kq];
    }
#pragma unroll
    for (int cs = 0; cs < 2; cs++) {
      f16x8 ah = cs ? Ah1 : Ah0;
      f16x8 al = cs ? Al1 : Al0;
#pragma unroll
      for (int s = 0; s < 2; s++) {
        acc[cs][s] = __builtin_amdgcn_mfma_f32_16x16x32_f16(al, Bh[s], acc[cs][s], 0, 0, 0);
        acc[cs][s] = __builtin_amdgcn_mfma_f32_16x16x32_f16(ah, Bl[s], acc[cs][s], 0, 0, 0);
        acc[cs][s] = __builtin_amdgcn_mfma_f32_16x16x32_f16(ah, Bh[s], acc[cs][s], 0, 0, 0);
      }
    }
  }
#pragma unroll
  for (int cs = 0; cs < 2; cs++)
#pragma unroll
    for (int s = 0; s < 2; s++) {
      int site = nB + s * 16 + ln;
      float4 g = make_float4(acc[cs][s][0], acc[cs][s][1], acc[cs][s][2], acc[cs][s][3]);
      *(float4*)&G[(pq * 2048 + site) * 128 + coW + cs * 16 + quad * 4] = g;
    }
}

// ---------- out: combine G per class, bias+relu, 1x1 conv to 3ch, splat ------
__global__ __launch_bounds__(256) void k_out(const float* __restrict__ G,
                                             const float* __restrict__ bc1,
                                             const float* __restrict__ w3,
                                             const float* __restrict__ b3,
                                             float* __restrict__ xhat,
                                             const float* __restrict__ loss_acc,
                                             float* __restrict__ out_loss) {
  __shared__ float Tb[9][128];
  __shared__ float part[9][3][8];
  __shared__ float vals[9][3];
  int bj = blockIdx.x, bi = blockIdx.y, b = blockIdx.z;
  int s = bi * 8 + bj;
  int n = b * 64 + s;
  int tid = threadIdx.x;
  if (bj == 0 && bi == 0 && b == 0 && tid == 0)
    out_loss[0] = loss_acc[0] * 1.25f / 131072.0f;
  int co = tid & 127, h = tid >> 7;
  const int rset[3][2] = {{0, 1}, {2, 2}, {3, 4}};
  const int rcnt[3] = {2, 1, 2};
  for (int cls = h; cls < 9; cls += 2) {
    int r = cls / 3, c = cls - r * 3;
    float sum = bc1[co];
    for (int iy = 0; iy < rcnt[r]; iy++) {
      int py = rset[r][iy];
      for (int ix = 0; ix < rcnt[c]; ix++) {
        int px = rset[c][ix];
        sum += G[((py * 5 + px) * 2048 + n) * 128 + co];
      }
    }
    Tb[cls][co] = fmaxf(sum, 0.f);
  }
  __syncthreads();
  if (tid < 216) {
    int cls = tid / 24, rem = tid - cls * 24;
    int cc = rem >> 3, seg = rem & 7;
    float ss = 0.f;
#pragma unroll
    for (int d = 0; d < 16; d++) ss = fmaf(w3[cc * 128 + seg * 16 + d], Tb[cls][seg * 16 + d], ss);
    part[cls][cc][seg] = ss;
  }
  __syncthreads();
  if (tid < 27) {
    int cls = tid / 3, cc = tid - cls * 3;
    float ss = b3[cc];
#pragma unroll
    for (int seg = 0; seg < 8; seg++) ss += part[cls][cc][seg];
    vals[cls][cc] = ss;
  }
  __syncthreads();
  for (int i = tid; i < 768; i += 256) {
    int cc = i >> 8, p = i & 255;
    int ry = p >> 4, rx = p & 15;
    int rcls = (ry == 0) ? 0 : ((ry == 15) ? 2 : 1);
    int ccls = (rx == 0) ? 0 : ((rx == 15) ? 2 : 1);
    xhat[((b * 3 + cc) * 128 + bi * 16 + ry) * 128 + bj * 16 + rx] =
        vals[rcls * 3 + ccls][cc];
  }
}

extern "C" void kernel_launch(void* const* d_in, const int* in_sizes, int n_in,
                              void* d_out, int out_size, void* d_ws, size_t ws_size,
                              hipStream_t stream) {
  const float* x   = (const float*)d_in[0];
  const float* w1  = (const float*)d_in[1];
  const float* b1  = (const float*)d_in[2];
  const float* w2  = (const float*)d_in[3];
  const float* b2  = (const float*)d_in[4];
  const float* wp  = (const float*)d_in[5];
  const float* pb  = (const float*)d_in[6];
  const float* cb  = (const float*)d_in[7];
  const float* wd  = (const float*)d_in[8];
  const float* db  = (const float*)d_in[9];
  const float* wc1 = (const float*)d_in[10];
  const float* bc1 = (const float*)d_in[11];
  const float* wc2 = (const float*)d_in[12];
  const float* bc2 = (const float*)d_in[13];
  float* out = (float*)d_out;
  float* ws  = (float*)d_ws;

  // workspace (float offsets):
  _Float16* h1h = (_Float16*)(ws);             // [0, 8388640) f16 plane (+tail)
  float* h2a    = ws + 16777280;               // 4194304
  _Float16* Wh  = (_Float16*)(ws + 20971584);  // 73728 fl
  _Float16* Wl  = (_Float16*)(ws + 21045312);  // 73728 fl
  float* w1t    = ws + 21119040;               // 3456
  float* wpT    = ws + 21122496;               // 8192
  float* wdT    = ws + 21130688;               // 8192
  float* cbT    = ws + 21138880;               // 32768
  _Float16* Ahd = (_Float16*)(ws + 21171648);  // 204800 fl
  _Float16* Ald = (_Float16*)(ws + 21376448);  // 204800 fl
  float* h2b    = ws + 21581248;               // 4194304 -> end 25775552
  // overlays inside dead h1h region (valid after conv2):
  float* G       = ws;                         // [0, 6553600)
  _Float16* Yh   = (_Float16*)(ws + 6553600);  // 131136 fl (2049*128 f16)
  _Float16* Yl   = (_Float16*)(ws + 6684736);  // 131136 fl
  float* lossacc = ws + 6815872;               // 1

  float* o_xhat = out;
  float* o_idx  = out + 1572864;
  float* o_loss = out + 1574912;
  float* o_ze   = out + 1574913;

  static bool s_attr_done = false;
  if (!s_attr_done) {
    (void)hipFuncSetAttribute((const void*)k_conv2,
                              hipFuncAttributeMaxDynamicSharedMemorySize, C2_LDS);
    s_attr_done = true;
  }

  k_prep<<<dim3(153), 256, 0, stream>>>(w2, w1, wp, wd, wc1, cb,
                                        w1t, wpT, wdT, cbT, Ahd, Ald, Wh, Wl, h1h);
  k_conv1<<<dim3(4, 16, 32), 256, 0, stream>>>(x, w1t, b1, h1h);
  k_conv2<<<dim3(512), 512, C2_LDS, stream>>>(h1h, Wh, Wl, h2a, h2b);
  k_poolproj<<<dim3(128), 256, 0, stream>>>(h2a, h2b, b2, wpT, pb, o_ze, lossacc);
  k_vqdproj<<<dim3(2048), 256, 0, stream>>>(o_ze, cbT, cb, wdT, db, o_idx, Yh, Yl, lossacc);
  k_dec<<<dim3(1600), 256, 0, stream>>>(Yh, Yl, Ahd, Ald, G);
  k_out<<<dim3(8, 8, 32), 256, 0, stream>>>(G, bc1, wc2, bc2, o_xhat, lossacc, o_loss);
}

// Round 9
// 242.290 us; speedup vs baseline: 1.0416x; 1.0416x over previous
//
#include <hip/hip_runtime.h>
#include <math.h>

// ---------------------------------------------------------------------------
// VQVAE forward. v17b: identical to v17 (round-8 bench died at container
// level with no kernel signal; audit found no OOB/hang mechanism).
// conv2 compute phase made 100% LDS-fed (m97 pattern): v13/v15/v16 proved
// occupancy irrelevant (8..32 waves/CU all ~46-60 us); the cost that scales
// with the tap loop (0.18 us/MFMA-unit, 11x MFMA floor) is the per-tap
// GLOBAL weight loads + in-order vmcnt waits inside compute. v17: blocks
// split by output co-half (512 = b x ohq x cohalf; full sums); per step BOTH
// act tile (37.4 KB) and the step's weight slice (74.9 KB padded) are staged
// via global_load_lds, one drain barrier, then compute is pure ds_read+MFMA.
// Weights pre-transposed by k_prep into [pl][tap][ci8g][co]x8. 2 barriers
// per step, 112.3 KB LDS. poolproj is the v14 single-h2 form.
// ---------------------------------------------------------------------------

typedef _Float16 f16x8 __attribute__((ext_vector_type(8)));
typedef float f32x4 __attribute__((ext_vector_type(4)));

#define H1N 16777216        // elements in h1 plane; zero tail after
#define YTAIL (2048 * 128)  // zero page in Yh/Yl for OOB shifts

// ---------- prep: A-agg (0..127), W-layout (128..143), cbT (144..151), misc -
__global__ __launch_bounds__(256) void k_prep(const float* __restrict__ w2,
                                              const float* __restrict__ w1,
                                              const float* __restrict__ wp,
                                              const float* __restrict__ wd,
                                              const float* __restrict__ wd1,
                                              const float* __restrict__ cb,
                                              float* __restrict__ w1t,
                                              float* __restrict__ wpT,
                                              float* __restrict__ wdT,
                                              float* __restrict__ cbT,
                                              _Float16* __restrict__ Ah,
                                              _Float16* __restrict__ Al,
                                              _Float16* __restrict__ WS,
                                              _Float16* __restrict__ h1h) {
  int bx = blockIdx.x, tid = threadIdx.x;
  if (bx < 128) {  // ---- A aggregation, block = co, lanes = ci (writes coalesced)
    __shared__ float wrow[1152];
    int co = bx;
    for (int i = tid; i < 1152; i += 256) wrow[i] = wd1[co * 1152 + i];
    __syncthreads();
    if (tid < 128) {
      int ci = tid;
      float w[9];
#pragma unroll
      for (int t = 0; t < 9; t++) w[t] = wrow[ci * 9 + t];
      float rx[3][5];
#pragma unroll
      for (int ky = 0; ky < 3; ky++) {
        float a0 = w[ky * 3 + 0], a1 = w[ky * 3 + 1], a2 = w[ky * 3 + 2];
        rx[ky][0] = a0; rx[ky][1] = a1 + a2; rx[ky][2] = a0 + a1 + a2;
        rx[ky][3] = a0 + a1; rx[ky][4] = a2;
      }
#pragma unroll
      for (int px = 0; px < 5; px++) {
        float s0 = rx[0][px], s1 = rx[1][px], s2 = rx[2][px];
        float ry[5];
        ry[0] = s0; ry[1] = s1 + s2; ry[2] = s0 + s1 + s2; ry[3] = s0 + s1; ry[4] = s2;
#pragma unroll
        for (int py = 0; py < 5; py++) {
          int pq = py * 5 + px;
          float v = ry[py];
          _Float16 h = (_Float16)v;
          int o = (pq * 128 + co) * 128 + ci;
          Ah[o] = h;
          Al[o] = (_Float16)(v - (float)h);
        }
      }
    }
    return;
  }
  if (bx < 144) {  // ---- W layout for conv2 staging: [pl][tap][ci8g][co]x8
    __shared__ float wst[9216];
    int co0 = (bx - 128) * 8;
    for (int i = tid; i < 9216; i += 256) wst[i] = w2[co0 * 1152 + i];
    __syncthreads();
    for (int i = tid; i < 9216; i += 256) {
      int co = i / 1152, r = i - co * 1152;
      int tap = r >> 7, ci = r & 127;
      float v = wst[co * 1152 + ci * 9 + tap];
      _Float16 h = (_Float16)v;
      int og = ((tap * 16 + (ci >> 3)) * 128 + co0 + co) * 8 + (ci & 7);
      WS[og] = h;                                   // pl = 0 (high)
      WS[og + 147456] = (_Float16)(v - (float)h);   // pl = 1 (low); 9*16*128*8
    }
    return;
  }
  if (bx < 152) {  // ---- cbT tile transpose (64 k x 64 d), padded LDS
    __shared__ float cbs[64 * 65];
    int k0 = (bx - 144) * 64;
    for (int i = tid; i < 4096; i += 256) {
      int k = i >> 6, d = i & 63;
      cbs[k * 65 + d] = cb[(k0 + k) * 64 + d];
    }
    __syncthreads();
    for (int i = tid; i < 4096; i += 256) {
      int d = i >> 6, k = i & 63;
      cbT[d * 512 + k0 + k] = cbs[k * 65 + d];
    }
    return;
  }
  // ---- misc small transposes + h1 zero tail (writes lane-contiguous)
  for (int i = tid; i < 3456; i += 256) {  // w1t[t][co] = w1[co][t]
    int co = i & 127, t = i >> 7;
    w1t[t * 128 + co] = w1[co * 27 + t];
  }
  for (int i = tid; i < 8192; i += 256) {  // wpT[k][d] = wp[d][k]
    int d = i & 63, k = i >> 6;
    wpT[k * 64 + d] = wp[d * 128 + k];
  }
  for (int i = tid; i < 8192; i += 256) {  // wdT[d][co] = wd[co][d]
    int co = i & 127, d = i >> 7;
    wdT[d * 128 + co] = wd[co * 64 + d];
  }
  if (tid < 64) h1h[H1N + tid] = (_Float16)0.f;
}

// ---------- conv1: (32,3,128,128) -> h1 f16 [g][b][oh][ow][8ci] -------------
__global__ __launch_bounds__(256) void k_conv1(const float* __restrict__ x,
                                               const float* __restrict__ w1t,
                                               const float* __restrict__ b1,
                                               _Float16* __restrict__ h1h) {
  __shared__ float E[3][9][68];
  __shared__ float O[3][9][68];
  int co_t = blockIdx.x, oh_t = blockIdx.y, b = blockIdx.z;
  int oh0 = oh_t * 4;
  int tid = threadIdx.x;
  int wv = __builtin_amdgcn_readfirstlane(tid >> 6);
  int l = tid & 63;
  int coB = co_t * 32 + wv * 8;

  for (int idx = tid; idx < 1728; idx += 256) {
    int p = idx & 63, r = idx >> 6;
    int ci = r / 9, lr = r - ci * 9;
    int ih = 2 * oh0 - 1 + lr;
    float2 v = make_float2(0.f, 0.f);
    if ((unsigned)ih < 128u)
      v = *(const float2*)&x[((b * 3 + ci) * 128 + ih) * 128 + 2 * p];
    E[ci][lr][p] = v.x;
    O[ci][lr][p + 1] = v.y;
  }
  if (tid < 27) {
    int ci = tid / 9, lr = tid - ci * 9;
    O[ci][lr][0] = 0.f;
  }
  __syncthreads();

  int ohl = l >> 4, ow0 = (l & 15) * 4;
  int oh = oh0 + ohl;
  float4 acc[8];
#pragma unroll
  for (int q = 0; q < 8; q++) {
    float bv = b1[coB + q];
    acc[q] = make_float4(bv, bv, bv, bv);
  }
#pragma unroll
  for (int ci = 0; ci < 3; ci++) {
#pragma unroll
    for (int ky = 0; ky < 3; ky++) {
      int lr = 2 * ohl + ky;
      float4 ev = *(float4*)&E[ci][lr][ow0];
      float4 od = *(float4*)&O[ci][lr][ow0];
      float o4 = O[ci][lr][ow0 + 4];
      const float* wr = w1t + (ci * 9 + ky * 3) * 128 + coB;
#pragma unroll
      for (int q = 0; q < 8; q++) {
        float wa = wr[q], wb = wr[128 + q], wc = wr[256 + q];
        acc[q].x = fmaf(wa, od.x, acc[q].x);
        acc[q].x = fmaf(wb, ev.x, acc[q].x);
        acc[q].x = fmaf(wc, od.y, acc[q].x);
        acc[q].y = fmaf(wa, od.y, acc[q].y);
        acc[q].y = fmaf(wb, ev.y, acc[q].y);
        acc[q].y = fmaf(wc, od.z, acc[q].y);
        acc[q].z = fmaf(wa, od.z, acc[q].z);
        acc[q].z = fmaf(wb, ev.z, acc[q].z);
        acc[q].z = fmaf(wc, od.w, acc[q].z);
        acc[q].w = fmaf(wa, od.w, acc[q].w);
        acc[q].w = fmaf(wb, ev.w, acc[q].w);
        acc[q].w = fmaf(wc, o4,   acc[q].w);
      }
    }
  }
  int g = coB >> 3;
  int pbase = ((g * 32 + b) * 64 + oh) * 64;
#pragma unroll
  for (int oi = 0; oi < 4; oi++) {
    f16x8 hv;
#pragma unroll
    for (int q = 0; q < 8; q++)
      hv[q] = (_Float16)fmaxf(((const float*)&acc[q])[oi], 0.f);
    *(f16x8*)&h1h[(pbase + ow0 + oi) * 8] = hv;
  }
}

// ---------- conv2: all-LDS compute; acts + weights staged via gload_lds -----
// grid 512 = (b(32) x ohq(8) x cohalf(2)); block 512 = 8 waves. wave w:
// cw = w&1 (co-group of 32 within the 64-co half), rw = w>>1 (output row).
// Wave computes 32co x 32px of row oh0+rw; acc[cs 2][sc 2].
// LDS: acts [0, 37440 B): chunk (g*9+r)*65 + (ph?33+u:u), g=ci8(4), r=row(9).
//      weights [37440, 112320 B): chunk ((pl*9+t)*4+quad)*65 + co_in_64
//      (65-padded; pad slot stages clamped dup). Per step: stage acts(step) +
//      weights(step) -> barrier(drain) -> compute (pure ds_read+MFMA) ->
//      barrier. Zero global loads in compute: no per-tap vmcnt stalls.
#define C2_ACHUNK 2340
#define C2_WCHUNK 4680
#define C2_WOFF (C2_ACHUNK * 8)               // f16 offset of weight region
#define C2_LDSB ((C2_ACHUNK + C2_WCHUNK) * 16)  // 112320 bytes
#define C2_STEP 4194304                       // h1 advance per +32ci step
#define C2_WADV 4096                          // WS f16 advance per step

__global__ __launch_bounds__(512, 2) void k_conv2(const _Float16* __restrict__ h1h,
                                                  const _Float16* __restrict__ WS,
                                                  const float* __restrict__ b2,
                                                  float* __restrict__ h2) {
  extern __shared__ _Float16 L[];
  int bx = blockIdx.x;
  int cohalf = bx & 1;
  int bq = bx >> 1;
  int b = bq >> 3, ohq = bq & 7;
  int oh0 = ohq * 4;
  int tid = threadIdx.x;
  int w = tid >> 6, l = tid & 63;
  int cw = w & 1, rw = w >> 1;
  int ln = l & 15, quad = l >> 4;

  // ---- act staging descriptors: 5 chunks/thread (tail tid<292) ----
  int cursA[5];
  int advA[5];
#pragma unroll
  for (int k = 0; k < 5; k++) {
    int c = (k < 4) ? (tid + k * 512) : (2048 + tid);
    if (c < C2_ACHUNK) {
      int q = c / 65, rem = c - q * 65;
      int ph = rem >= 33;
      int u = ph ? rem - 33 : rem;
      int r = q % 9, g = q / 9;
      int iw = ph ? 2 * u : 2 * u - 1;
      int ih = 2 * oh0 - 1 + r;
      bool ok = (ih >= 0) && (iw >= 0) && (iw < 64);
      cursA[k] = ok ? ((g * 32 + b) * 64 + ih) * 512 + iw * 8 : H1N;
      advA[k] = ok ? C2_STEP : 0;
    } else {
      cursA[k] = H1N;
      advA[k] = 0;
    }
  }
  // ---- weight staging descriptors: 10 chunks/thread (tail tid<72) ----
  int cursW[10];
#pragma unroll
  for (int k = 0; k < 10; k++) {
    int c = (k < 9) ? (tid + k * 512) : (4608 + tid);
    if (c < C2_WCHUNK) {
      int q65 = c / 65, u = c - q65 * 65;
      if (u > 63) u = 63;  // pad slot: stage harmless duplicate
      int pl = q65 >= 36;
      int r36 = q65 - pl * 36;
      int t = r36 >> 2, ci8 = r36 & 3;
      cursW[k] = ((pl * 9 + t) * 16 + ci8) * 1024 + (cohalf * 64 + u) * 8;
    } else {
      cursW[k] = 0;
    }
  }

  f32x4 acc[2][2] = {};  // [cs][sc]
  for (int step = 0; step < 4; step++) {
    if (step) __syncthreads();  // prior compute done reading L
    // ---- stage acts(step) ----
#pragma unroll
    for (int k = 0; k < 4; k++) {
      __builtin_amdgcn_global_load_lds(
          (const __attribute__((address_space(1))) void*)(h1h + cursA[k]),
          (__attribute__((address_space(3))) void*)&L[(tid + k * 512) * 8],
          16, 0, 0);
      cursA[k] += advA[k];
    }
    if (tid < 292)
      __builtin_amdgcn_global_load_lds(
          (const __attribute__((address_space(1))) void*)(h1h + cursA[4]),
          (__attribute__((address_space(3))) void*)&L[(2048 + tid) * 8],
          16, 0, 0);
    cursA[4] += advA[4];
    // ---- stage weights(step) ----
#pragma unroll
    for (int k = 0; k < 9; k++) {
      __builtin_amdgcn_global_load_lds(
          (const __attribute__((address_space(1))) void*)(WS + cursW[k]),
          (__attribute__((address_space(3))) void*)&L[C2_WOFF +
                                                     (tid + k * 512) * 8],
          16, 0, 0);
      cursW[k] += C2_WADV;
    }
    if (tid < 72)
      __builtin_amdgcn_global_load_lds(
          (const __attribute__((address_space(1))) void*)(WS + cursW[9]),
          (__attribute__((address_space(3))) void*)&L[C2_WOFF +
                                                     (4608 + tid) * 8],
          16, 0, 0);
    cursW[9] += C2_WADV;
    __syncthreads();  // drain: acts + weights resident

    // ---- compute: pure LDS + MFMA ----
#pragma unroll
    for (int ky = 0; ky < 3; ky++) {
#pragma unroll
      for (int kx = 0; kx < 3; kx++) {
        int t = ky * 3 + kx;
        int r = 2 * rw + ky;
        int abase = (quad * 9 + r) * 65;
        int wb = (t * 4 + quad) * 65 + cw * 32 + ln;
        f16x8 Ah0 = *(const f16x8*)&L[C2_WOFF + wb * 8];
        f16x8 Ah1 = *(const f16x8*)&L[C2_WOFF + (wb + 16) * 8];
        f16x8 Al0 = *(const f16x8*)&L[C2_WOFF + (wb + 2340) * 8];
        f16x8 Al1 = *(const f16x8*)&L[C2_WOFF + (wb + 2356) * 8];
#pragma unroll
        for (int sc = 0; sc < 2; sc++) {
          int owl = sc * 16 + ln;
          int uoff = (kx == 1) ? (33 + owl) : (owl + (kx == 2));
          f16x8 Bh = *(const f16x8*)&L[(abase + uoff) * 8];
          acc[0][sc] = __builtin_amdgcn_mfma_f32_16x16x32_f16(Al0, Bh, acc[0][sc], 0, 0, 0);
          acc[0][sc] = __builtin_amdgcn_mfma_f32_16x16x32_f16(Ah0, Bh, acc[0][sc], 0, 0, 0);
          acc[1][sc] = __builtin_amdgcn_mfma_f32_16x16x32_f16(Al1, Bh, acc[1][sc], 0, 0, 0);
          acc[1][sc] = __builtin_amdgcn_mfma_f32_16x16x32_f16(Ah1, Bh, acc[1][sc], 0, 0, 0);
        }
      }
    }
  }
  // epilogue: full sums for this co-half; bias+relu here
  int oh = oh0 + rw;
#pragma unroll
  for (int cs = 0; cs < 2; cs++)
#pragma unroll
    for (int sc = 0; sc < 2; sc++) {
      int ow = sc * 16 + ln;
#pragma unroll
      for (int r2 = 0; r2 < 4; r2++) {
        int co = cohalf * 64 + cw * 32 + cs * 16 + quad * 4 + r2;
        h2[((b * 128 + co) * 32 + oh) * 32 + ow] = fmaxf(acc[cs][sc][r2] + b2[co], 0.f);
      }
    }
}

// ---------- pool(4x4 mean) + proj(1x1,128->64); grid 128 (b x quarter) ------
__global__ __launch_bounds__(256) void k_poolproj(const float* __restrict__ h2,
                                                  const float* __restrict__ wpT,
                                                  const float* __restrict__ pb,
                                                  float* __restrict__ z_e_out,
                                                  float* __restrict__ lossacc) {
  __shared__ float hp[128][16];
  __shared__ float Ws[128][64];
  int bx = blockIdx.x, tid = threadIdx.x;
  int b = bx >> 2, quarter = bx & 3;
  if (bx == 0 && tid == 0) lossacc[0] = 0.f;
  for (int i = tid; i < 8192; i += 256) Ws[i >> 6][i & 63] = wpT[i];
  for (int i = tid; i < 2048; i += 256) {
    int ci = i >> 4, pl = i & 15;
    int pi = quarter * 16 + pl;
    int bi = pi >> 3, bj = pi & 7;
    const float* src = &h2[((b * 128 + ci) * 32 + bi * 4) * 32 + bj * 4];
    float4 r0 = *(const float4*)src;
    float4 r1 = *(const float4*)(src + 32);
    float4 r2 = *(const float4*)(src + 64);
    float4 r3 = *(const float4*)(src + 96);
    float s = r0.x + r0.y + r0.z + r0.w + r1.x + r1.y + r1.z + r1.w +
              r2.x + r2.y + r2.z + r2.w + r3.x + r3.y + r3.z + r3.w;
    hp[ci][pl] = s * 0.0625f;
  }
  __syncthreads();
  int d = tid >> 2, s0 = (tid & 3) * 4;
  float4 acc = make_float4(0.f, 0.f, 0.f, 0.f);
  for (int k = 0; k < 128; k++) {
    float a = Ws[k][d];
    float4 h = *(float4*)&hp[k][s0];
    acc.x = fmaf(a, h.x, acc.x);
    acc.y = fmaf(a, h.y, acc.y);
    acc.z = fmaf(a, h.z, acc.z);
    acc.w = fmaf(a, h.w, acc.w);
  }
  float bv = pb[d];
  float4 r4 = make_float4(acc.x + bv, acc.y + bv, acc.z + bv, acc.w + bv);
  *(float4*)&z_e_out[(b * 64 + d) * 64 + quarter * 16 + s0] = r4;
}

// ---------- VQ argmin + loss + dproj; grid 2048 x 256 (4 waves) -------------
__global__ __launch_bounds__(256) void k_vqdproj(const float* __restrict__ z_e,
                                                 const float* __restrict__ cbT,
                                                 const float* __restrict__ cb,
                                                 const float* __restrict__ wdT,
                                                 const float* __restrict__ db,
                                                 float* __restrict__ idx_f,
                                                 _Float16* __restrict__ Yh,
                                                 _Float16* __restrict__ Yl,
                                                 float* __restrict__ loss_acc) {
  __shared__ float zs[64];
  __shared__ float zqv[64];
  __shared__ double wbst[4];
  __shared__ int wbi[4];
  int n = blockIdx.x, tid = threadIdx.x;
  int b = n >> 6, pi = n & 63;
  if (tid < 64) zs[tid] = z_e[(b * 64 + tid) * 64 + pi];
  if (n == 0 && tid < 64) {  // zero tail page for shifted reads in k_dec
    Yh[YTAIL + tid] = (_Float16)0.f;
    Yh[YTAIL + 64 + tid] = (_Float16)0.f;
    Yl[YTAIL + tid] = (_Float16)0.f;
    Yl[YTAIL + 64 + tid] = (_Float16)0.f;
  }
  __syncthreads();
  int w = tid >> 6, lane = tid & 63;
  double best = 1e300;
  int bi = 0;
#pragma unroll
  for (int j = 0; j < 2; j++) {
    int k = w * 128 + j * 64 + lane;
    double a0 = 0.0, a1 = 0.0, a2 = 0.0, a3 = 0.0;
#pragma unroll 4
    for (int d = 0; d < 64; d += 4) {
      double f0 = (double)zs[d] - (double)cbT[d * 512 + k];
      double f1 = (double)zs[d + 1] - (double)cbT[(d + 1) * 512 + k];
      double f2 = (double)zs[d + 2] - (double)cbT[(d + 2) * 512 + k];
      double f3 = (double)zs[d + 3] - (double)cbT[(d + 3) * 512 + k];
      a0 = fma(f0, f0, a0);
      a1 = fma(f1, f1, a1);
      a2 = fma(f2, f2, a2);
      a3 = fma(f3, f3, a3);
    }
    double acc = (a0 + a1) + (a2 + a3);
    if (acc < best) { best = acc; bi = k; }
  }
  for (int m = 1; m < 64; m <<= 1) {
    double ob = __shfl_xor(best, m, 64);
    int oi = __shfl_xor(bi, m, 64);
    if (ob < best || (ob == best && oi < bi)) { best = ob; bi = oi; }
  }
  if (lane == 0) { wbst[w] = best; wbi[w] = bi; }
  __syncthreads();
  best = wbst[0];
  bi = wbi[0];
#pragma unroll
  for (int q = 1; q < 4; q++) {
    double ob = wbst[q];
    int oi = wbi[q];
    if (ob < best || (ob == best && oi < bi)) { best = ob; bi = oi; }
  }
  if (tid < 64) {  // wave 0: loss + zq staging
    float zq_l = cb[bi * 64 + tid];
    float e = zq_l - zs[tid];
    float sq = e * e;
    for (int m = 1; m < 64; m <<= 1) sq += __shfl_xor(sq, m, 64);
    if (tid == 0) {
      idx_f[n] = (float)bi;
      atomicAdd(loss_acc, sq);
    }
    zqv[tid] = zq_l;
  }
  __syncthreads();
  if (tid < 128) {  // dproj: one co per thread
    float a = db[tid];
#pragma unroll 4
    for (int d = 0; d < 64; d++) a = fmaf(wdT[d * 128 + tid], zqv[d], a);
    float y = fmaxf(a, 0.f);
    _Float16 h = (_Float16)y;
    Yh[n * 128 + tid] = h;
    Yl[n * 128 + tid] = (_Float16)(y - (float)h);
  }
}

// ---------- dec: f16-split MFMA, G[pq][n][co] = A_pq * Yshift ----------
__global__ __launch_bounds__(256) void k_dec(const _Float16* __restrict__ Yh,
                                             const _Float16* __restrict__ Yl,
                                             const _Float16* __restrict__ Ah,
                                             const _Float16* __restrict__ Al,
                                             float* __restrict__ G) {
  int bxx = blockIdx.x;
  int pq = bxx >> 6, n_t = bxx & 63;
  int w = threadIdx.x >> 6, l = threadIdx.x & 63;
  int ln = l & 15, quad = l >> 4;
  int coW = w * 32;
  int nB = n_t * 32;
  int py = pq / 5, px = pq - py * 5;
  int dy = (py == 0) ? -1 : ((py == 4) ? 1 : 0);
  int dx = (px == 0) ? -1 : ((px == 4) ? 1 : 0);
  int src[2];
#pragma unroll
  for (int s = 0; s < 2; s++) {
    int n = nB + s * 16 + ln;
    int bb = n >> 6, s6 = n & 63;
    int sy = (s6 >> 3) + dy, sx = (s6 & 7) + dx;
    bool ok = ((unsigned)sy < 8u) && ((unsigned)sx < 8u);
    src[s] = ok ? ((bb * 64 + sy * 8 + sx) * 128) : YTAIL;
  }
  int kq = quad * 8;
  f32x4 acc[2][2] = {};
#pragma unroll 2
  for (int ci0 = 0; ci0 < 128; ci0 += 32) {
    const int wbase = (pq * 128 + coW + ln) * 128 + ci0 + kq;
    f16x8 Ah0 = *(const f16x8*)&Ah[wbase];
    f16x8 Al0 = *(const f16x8*)&Al[wbase];
    f16x8 Ah1 = *(const f16x8*)&Ah[wbase + 2048];
    f16x8 Al1 = *(const f16x8*)&Al[wbase + 2048];
    f16x8 Bh[2], Bl[2];
#pragma unroll
    for (int s = 0; s < 2; s++) {
      Bh[s] = *(const f16x8*)&Yh[src[s] + ci0 + kq];
      Bl[s] = *(const f16x8*)&Yl[src[s] + ci0 + kq];
    }
#pragma unroll
    for (int cs = 0; cs < 2; cs++) {
      f16x8 ah = cs ? Ah1 : Ah0;
      f16x8 al = cs ? Al1 : Al0;
#pragma unroll
      for (int s = 0; s < 2; s++) {
        acc[cs][s] = __builtin_amdgcn_mfma_f32_16x16x32_f16(al, Bh[s], acc[cs][s], 0, 0, 0);
        acc[cs][s] = __builtin_amdgcn_mfma_f32_16x16x32_f16(ah, Bl[s], acc[cs][s], 0, 0, 0);
        acc[cs][s] = __builtin_amdgcn_mfma_f32_16x16x32_f16(ah, Bh[s], acc[cs][s], 0, 0, 0);
      }
    }
  }
#pragma unroll
  for (int cs = 0; cs < 2; cs++)
#pragma unroll
    for (int s = 0; s < 2; s++) {
      int site = nB + s * 16 + ln;
      float4 g = make_float4(acc[cs][s][0], acc[cs][s][1], acc[cs][s][2], acc[cs][s][3]);
      *(float4*)&G[(pq * 2048 + site) * 128 + coW + cs * 16 + quad * 4] = g;
    }
}

// ---------- out: combine G per class, bias+relu, 1x1 conv to 3ch, splat ------
__global__ __launch_bounds__(256) void k_out(const float* __restrict__ G,
                                             const float* __restrict__ bc1,
                                             const float* __restrict__ w3,
                                             const float* __restrict__ b3,
                                             float* __restrict__ xhat,
                                             const float* __restrict__ loss_acc,
                                             float* __restrict__ out_loss) {
  __shared__ float Tb[9][128];
  __shared__ float part[9][3][8];
  __shared__ float vals[9][3];
  int bj = blockIdx.x, bi = blockIdx.y, b = blockIdx.z;
  int s = bi * 8 + bj;
  int n = b * 64 + s;
  int tid = threadIdx.x;
  if (bj == 0 && bi == 0 && b == 0 && tid == 0)
    out_loss[0] = loss_acc[0] * 1.25f / 131072.0f;
  int co = tid & 127, h = tid >> 7;
  const int rset[3][2] = {{0, 1}, {2, 2}, {3, 4}};
  const int rcnt[3] = {2, 1, 2};
  for (int cls = h; cls < 9; cls += 2) {
    int r = cls / 3, c = cls - r * 3;
    float sum = bc1[co];
    for (int iy = 0; iy < rcnt[r]; iy++) {
      int py = rset[r][iy];
      for (int ix = 0; ix < rcnt[c]; ix++) {
        int px = rset[c][ix];
        sum += G[((py * 5 + px) * 2048 + n) * 128 + co];
      }
    }
    Tb[cls][co] = fmaxf(sum, 0.f);
  }
  __syncthreads();
  if (tid < 216) {
    int cls = tid / 24, rem = tid - cls * 24;
    int cc = rem >> 3, seg = rem & 7;
    float ss = 0.f;
#pragma unroll
    for (int d = 0; d < 16; d++) ss = fmaf(w3[cc * 128 + seg * 16 + d], Tb[cls][seg * 16 + d], ss);
    part[cls][cc][seg] = ss;
  }
  __syncthreads();
  if (tid < 27) {
    int cls = tid / 3, cc = tid - cls * 3;
    float ss = b3[cc];
#pragma unroll
    for (int seg = 0; seg < 8; seg++) ss += part[cls][cc][seg];
    vals[cls][cc] = ss;
  }
  __syncthreads();
  for (int i = tid; i < 768; i += 256) {
    int cc = i >> 8, p = i & 255;
    int ry = p >> 4, rx = p & 15;
    int rcls = (ry == 0) ? 0 : ((ry == 15) ? 2 : 1);
    int ccls = (rx == 0) ? 0 : ((rx == 15) ? 2 : 1);
    xhat[((b * 3 + cc) * 128 + bi * 16 + ry) * 128 + bj * 16 + rx] =
        vals[rcls * 3 + ccls][cc];
  }
}

extern "C" void kernel_launch(void* const* d_in, const int* in_sizes, int n_in,
                              void* d_out, int out_size, void* d_ws, size_t ws_size,
                              hipStream_t stream) {
  const float* x   = (const float*)d_in[0];
  const float* w1  = (const float*)d_in[1];
  const float* b1  = (const float*)d_in[2];
  const float* w2  = (const float*)d_in[3];
  const float* b2  = (const float*)d_in[4];
  const float* wp  = (const float*)d_in[5];
  const float* pb  = (const float*)d_in[6];
  const float* cb  = (const float*)d_in[7];
  const float* wd  = (const float*)d_in[8];
  const float* db  = (const float*)d_in[9];
  const float* wc1 = (const float*)d_in[10];
  const float* bc1 = (const float*)d_in[11];
  const float* wc2 = (const float*)d_in[12];
  const float* bc2 = (const float*)d_in[13];
  float* out = (float*)d_out;
  float* ws  = (float*)d_ws;

  // workspace (float offsets):
  _Float16* h1h = (_Float16*)(ws);             // [0, 8388640) f16 plane (+tail)
  float* h2     = ws + 16777280;               // 4194304
  _Float16* WS  = (_Float16*)(ws + 20971584);  // 147456 fl (294912 f16)
  float* w1t    = ws + 21119040;               // 3456
  float* wpT    = ws + 21122496;               // 8192
  float* wdT    = ws + 21130688;               // 8192
  float* cbT    = ws + 21138880;               // 32768
  _Float16* Ahd = (_Float16*)(ws + 21171648);  // 204800 fl
  _Float16* Ald = (_Float16*)(ws + 21376448);  // 204800 fl -> end 21581248
  // overlays inside dead h1h region (valid after conv2):
  float* G       = ws;                         // [0, 6553600)
  _Float16* Yh   = (_Float16*)(ws + 6553600);  // 131136 fl (2049*128 f16)
  _Float16* Yl   = (_Float16*)(ws + 6684736);  // 131136 fl
  float* lossacc = ws + 6815872;               // 1

  float* o_xhat = out;
  float* o_idx  = out + 1572864;
  float* o_loss = out + 1574912;
  float* o_ze   = out + 1574913;

  static bool s_attr_done = false;
  if (!s_attr_done) {
    (void)hipFuncSetAttribute((const void*)k_conv2,
                              hipFuncAttributeMaxDynamicSharedMemorySize, C2_LDSB);
    s_attr_done = true;
  }

  k_prep<<<dim3(153), 256, 0, stream>>>(w2, w1, wp, wd, wc1, cb,
                                        w1t, wpT, wdT, cbT, Ahd, Ald, WS, h1h);
  k_conv1<<<dim3(4, 16, 32), 256, 0, stream>>>(x, w1t, b1, h1h);
  k_conv2<<<dim3(512), 512, C2_LDSB, stream>>>(h1h, WS, b2, h2);
  k_poolproj<<<dim3(128), 256, 0, stream>>>(h2, wpT, pb, o_ze, lossacc);
  k_vqdproj<<<dim3(2048), 256, 0, stream>>>(o_ze, cbT, cb, wdT, db, o_idx, Yh, Yl, lossacc);
  k_dec<<<dim3(1600), 256, 0, stream>>>(Yh, Yl, Ahd, Ald, G);
  k_out<<<dim3(8, 8, 32), 256, 0, stream>>>(G, bc1, wc2, bc2, o_xhat, lossacc, o_loss);
}

// Round 10
// 236.993 us; speedup vs baseline: 1.0648x; 1.0224x over previous
//
#include <hip/hip_runtime.h>
#include <math.h>

// ---------------------------------------------------------------------------
// VQVAE forward. v18: conv2 fat-step variant. v17b (all-LDS compute) landed
// ~38-40 us -- the residual cost is the per-step stage->drain-barrier
// serialization (8 full drains/block, no overlap possible with single
// weight buffer). v18 halves the drain count per output: blocks cover 8
// output rows (grid 256 = b x ohq(4) x cohalf), act tile 17 rows (70.7 KB)
// + weight slice (74.9 KB) = 145.6 KB single-buffer LDS; per-step compute
// doubles (144 MFMA/wave) at one drain each; total staged bytes/CU drop
// 898->582 KB. Per-acc MFMA order unchanged -> bit-identical output.
// ---------------------------------------------------------------------------

typedef _Float16 f16x8 __attribute__((ext_vector_type(8)));
typedef float f32x4 __attribute__((ext_vector_type(4)));

#define H1N 16777216        // elements in h1 plane; zero tail after
#define YTAIL (2048 * 128)  // zero page in Yh/Yl for OOB shifts

// ---------- prep: A-agg (0..127), W-layout (128..143), cbT (144..151), misc -
__global__ __launch_bounds__(256) void k_prep(const float* __restrict__ w2,
                                              const float* __restrict__ w1,
                                              const float* __restrict__ wp,
                                              const float* __restrict__ wd,
                                              const float* __restrict__ wd1,
                                              const float* __restrict__ cb,
                                              float* __restrict__ w1t,
                                              float* __restrict__ wpT,
                                              float* __restrict__ wdT,
                                              float* __restrict__ cbT,
                                              _Float16* __restrict__ Ah,
                                              _Float16* __restrict__ Al,
                                              _Float16* __restrict__ WS,
                                              _Float16* __restrict__ h1h) {
  int bx = blockIdx.x, tid = threadIdx.x;
  if (bx < 128) {  // ---- A aggregation, block = co, lanes = ci (writes coalesced)
    __shared__ float wrow[1152];
    int co = bx;
    for (int i = tid; i < 1152; i += 256) wrow[i] = wd1[co * 1152 + i];
    __syncthreads();
    if (tid < 128) {
      int ci = tid;
      float w[9];
#pragma unroll
      for (int t = 0; t < 9; t++) w[t] = wrow[ci * 9 + t];
      float rx[3][5];
#pragma unroll
      for (int ky = 0; ky < 3; ky++) {
        float a0 = w[ky * 3 + 0], a1 = w[ky * 3 + 1], a2 = w[ky * 3 + 2];
        rx[ky][0] = a0; rx[ky][1] = a1 + a2; rx[ky][2] = a0 + a1 + a2;
        rx[ky][3] = a0 + a1; rx[ky][4] = a2;
      }
#pragma unroll
      for (int px = 0; px < 5; px++) {
        float s0 = rx[0][px], s1 = rx[1][px], s2 = rx[2][px];
        float ry[5];
        ry[0] = s0; ry[1] = s1 + s2; ry[2] = s0 + s1 + s2; ry[3] = s0 + s1; ry[4] = s2;
#pragma unroll
        for (int py = 0; py < 5; py++) {
          int pq = py * 5 + px;
          float v = ry[py];
          _Float16 h = (_Float16)v;
          int o = (pq * 128 + co) * 128 + ci;
          Ah[o] = h;
          Al[o] = (_Float16)(v - (float)h);
        }
      }
    }
    return;
  }
  if (bx < 144) {  // ---- W layout for conv2 staging: [pl][tap][ci8g][co]x8
    __shared__ float wst[9216];
    int co0 = (bx - 128) * 8;
    for (int i = tid; i < 9216; i += 256) wst[i] = w2[co0 * 1152 + i];
    __syncthreads();
    for (int i = tid; i < 9216; i += 256) {
      int co = i / 1152, r = i - co * 1152;
      int tap = r >> 7, ci = r & 127;
      float v = wst[co * 1152 + ci * 9 + tap];
      _Float16 h = (_Float16)v;
      int og = ((tap * 16 + (ci >> 3)) * 128 + co0 + co) * 8 + (ci & 7);
      WS[og] = h;                                   // pl = 0 (high)
      WS[og + 147456] = (_Float16)(v - (float)h);   // pl = 1 (low); 9*16*128*8
    }
    return;
  }
  if (bx < 152) {  // ---- cbT tile transpose (64 k x 64 d), padded LDS
    __shared__ float cbs[64 * 65];
    int k0 = (bx - 144) * 64;
    for (int i = tid; i < 4096; i += 256) {
      int k = i >> 6, d = i & 63;
      cbs[k * 65 + d] = cb[(k0 + k) * 64 + d];
    }
    __syncthreads();
    for (int i = tid; i < 4096; i += 256) {
      int d = i >> 6, k = i & 63;
      cbT[d * 512 + k0 + k] = cbs[k * 65 + d];
    }
    return;
  }
  // ---- misc small transposes + h1 zero tail (writes lane-contiguous)
  for (int i = tid; i < 3456; i += 256) {  // w1t[t][co] = w1[co][t]
    int co = i & 127, t = i >> 7;
    w1t[t * 128 + co] = w1[co * 27 + t];
  }
  for (int i = tid; i < 8192; i += 256) {  // wpT[k][d] = wp[d][k]
    int d = i & 63, k = i >> 6;
    wpT[k * 64 + d] = wp[d * 128 + k];
  }
  for (int i = tid; i < 8192; i += 256) {  // wdT[d][co] = wd[co][d]
    int co = i & 127, d = i >> 7;
    wdT[d * 128 + co] = wd[co * 64 + d];
  }
  if (tid < 64) h1h[H1N + tid] = (_Float16)0.f;
}

// ---------- conv1: (32,3,128,128) -> h1 f16 [g][b][oh][ow][8ci] -------------
__global__ __launch_bounds__(256) void k_conv1(const float* __restrict__ x,
                                               const float* __restrict__ w1t,
                                               const float* __restrict__ b1,
                                               _Float16* __restrict__ h1h) {
  __shared__ float E[3][9][68];
  __shared__ float O[3][9][68];
  int co_t = blockIdx.x, oh_t = blockIdx.y, b = blockIdx.z;
  int oh0 = oh_t * 4;
  int tid = threadIdx.x;
  int wv = __builtin_amdgcn_readfirstlane(tid >> 6);
  int l = tid & 63;
  int coB = co_t * 32 + wv * 8;

  for (int idx = tid; idx < 1728; idx += 256) {
    int p = idx & 63, r = idx >> 6;
    int ci = r / 9, lr = r - ci * 9;
    int ih = 2 * oh0 - 1 + lr;
    float2 v = make_float2(0.f, 0.f);
    if ((unsigned)ih < 128u)
      v = *(const float2*)&x[((b * 3 + ci) * 128 + ih) * 128 + 2 * p];
    E[ci][lr][p] = v.x;
    O[ci][lr][p + 1] = v.y;
  }
  if (tid < 27) {
    int ci = tid / 9, lr = tid - ci * 9;
    O[ci][lr][0] = 0.f;
  }
  __syncthreads();

  int ohl = l >> 4, ow0 = (l & 15) * 4;
  int oh = oh0 + ohl;
  float4 acc[8];
#pragma unroll
  for (int q = 0; q < 8; q++) {
    float bv = b1[coB + q];
    acc[q] = make_float4(bv, bv, bv, bv);
  }
#pragma unroll
  for (int ci = 0; ci < 3; ci++) {
#pragma unroll
    for (int ky = 0; ky < 3; ky++) {
      int lr = 2 * ohl + ky;
      float4 ev = *(float4*)&E[ci][lr][ow0];
      float4 od = *(float4*)&O[ci][lr][ow0];
      float o4 = O[ci][lr][ow0 + 4];
      const float* wr = w1t + (ci * 9 + ky * 3) * 128 + coB;
#pragma unroll
      for (int q = 0; q < 8; q++) {
        float wa = wr[q], wb = wr[128 + q], wc = wr[256 + q];
        acc[q].x = fmaf(wa, od.x, acc[q].x);
        acc[q].x = fmaf(wb, ev.x, acc[q].x);
        acc[q].x = fmaf(wc, od.y, acc[q].x);
        acc[q].y = fmaf(wa, od.y, acc[q].y);
        acc[q].y = fmaf(wb, ev.y, acc[q].y);
        acc[q].y = fmaf(wc, od.z, acc[q].y);
        acc[q].z = fmaf(wa, od.z, acc[q].z);
        acc[q].z = fmaf(wb, ev.z, acc[q].z);
        acc[q].z = fmaf(wc, od.w, acc[q].z);
        acc[q].w = fmaf(wa, od.w, acc[q].w);
        acc[q].w = fmaf(wb, ev.w, acc[q].w);
        acc[q].w = fmaf(wc, o4,   acc[q].w);
      }
    }
  }
  int g = coB >> 3;
  int pbase = ((g * 32 + b) * 64 + oh) * 64;
#pragma unroll
  for (int oi = 0; oi < 4; oi++) {
    f16x8 hv;
#pragma unroll
    for (int q = 0; q < 8; q++)
      hv[q] = (_Float16)fmaxf(((const float*)&acc[q])[oi], 0.f);
    *(f16x8*)&h1h[(pbase + ow0 + oi) * 8] = hv;
  }
}

// ---------- conv2: fat-step all-LDS compute; 8 output rows per block --------
// grid 256 = (b(32) x ohq(4) x cohalf(2)); block 512 = 8 waves. wave w:
// cw = w&1 (co-group of 32 within the 64-co half), rw = w>>1 (row-pair:
// rows oh0+2rw, oh0+2rw+1). acc[cs 2][s 4], s = (row-in-pair<<1)|col-half.
// LDS: acts [0, 70720 B): chunk (g*17+r)*65 + (ph?33+u:u), g=ci8(4),
//      r=input row(17: ih=2*oh0-1+r).
//      weights [70720, 145600 B): chunk ((pl*9+t)*4+quad)*65 + co_in_64.
// Per step: stage acts+weights (gload_lds) -> barrier(drain) -> compute
// (pure ds_read+MFMA) -> barrier. 4 steps, 145.6 KB LDS, 1 block/CU
// (occupancy proven irrelevant: v13/v15/v16/v17).
#define C2_ACHUNK 4420                          // 4*17*65
#define C2_WCHUNK 4680
#define C2_WOFF (C2_ACHUNK * 8)                 // f16 offset of weight region
#define C2_LDSB ((C2_ACHUNK + C2_WCHUNK) * 16)  // 145600 bytes
#define C2_STEP 4194304                         // h1 advance per +32ci step
#define C2_WADV 4096                            // WS f16 advance per step

__global__ __launch_bounds__(512, 2) void k_conv2(const _Float16* __restrict__ h1h,
                                                  const _Float16* __restrict__ WS,
                                                  const float* __restrict__ b2,
                                                  float* __restrict__ h2) {
  extern __shared__ _Float16 L[];
  int bx = blockIdx.x;
  int cohalf = bx & 1;
  int bq = bx >> 1;
  int b = bq >> 2, ohq = bq & 3;
  int oh0 = ohq * 8;
  int tid = threadIdx.x;
  int w = tid >> 6, l = tid & 63;
  int cw = w & 1, rw = w >> 1;
  int ln = l & 15, quad = l >> 4;

  // ---- act staging descriptors: 9 chunks/thread (tail tid<324) ----
  int cursA[9];
  int advA[9];
#pragma unroll
  for (int k = 0; k < 9; k++) {
    int c = (k < 8) ? (tid + k * 512) : (4096 + tid);
    if (c < C2_ACHUNK) {
      int q = c / 65, rem = c - q * 65;
      int ph = rem >= 33;
      int u = ph ? rem - 33 : rem;
      int r = q % 17, g = q / 17;
      int iw = ph ? 2 * u : 2 * u - 1;
      int ih = 2 * oh0 - 1 + r;
      bool ok = (ih >= 0) && (iw >= 0) && (iw < 64);
      cursA[k] = ok ? ((g * 32 + b) * 64 + ih) * 512 + iw * 8 : H1N;
      advA[k] = ok ? C2_STEP : 0;
    } else {
      cursA[k] = H1N;
      advA[k] = 0;
    }
  }
  // ---- weight staging descriptors: 10 chunks/thread (tail tid<72) ----
  int cursW[10];
#pragma unroll
  for (int k = 0; k < 10; k++) {
    int c = (k < 9) ? (tid + k * 512) : (4608 + tid);
    if (c < C2_WCHUNK) {
      int q65 = c / 65, u = c - q65 * 65;
      if (u > 63) u = 63;  // pad slot: stage harmless duplicate
      int pl = q65 >= 36;
      int r36 = q65 - pl * 36;
      int t = r36 >> 2, ci8 = r36 & 3;
      cursW[k] = ((pl * 9 + t) * 16 + ci8) * 1024 + (cohalf * 64 + u) * 8;
    } else {
      cursW[k] = 0;
    }
  }

  f32x4 acc[2][4] = {};  // [cs][s]
  for (int step = 0; step < 4; step++) {
    if (step) __syncthreads();  // prior compute done reading L
    // ---- stage acts(step) ----
#pragma unroll
    for (int k = 0; k < 8; k++) {
      __builtin_amdgcn_global_load_lds(
          (const __attribute__((address_space(1))) void*)(h1h + cursA[k]),
          (__attribute__((address_space(3))) void*)&L[(tid + k * 512) * 8],
          16, 0, 0);
      cursA[k] += advA[k];
    }
    if (tid < 324)
      __builtin_amdgcn_global_load_lds(
          (const __attribute__((address_space(1))) void*)(h1h + cursA[8]),
          (__attribute__((address_space(3))) void*)&L[(4096 + tid) * 8],
          16, 0, 0);
    cursA[8] += advA[8];
    // ---- stage weights(step) ----
#pragma unroll
    for (int k = 0; k < 9; k++) {
      __builtin_amdgcn_global_load_lds(
          (const __attribute__((address_space(1))) void*)(WS + cursW[k]),
          (__attribute__((address_space(3))) void*)&L[C2_WOFF +
                                                     (tid + k * 512) * 8],
          16, 0, 0);
      cursW[k] += C2_WADV;
    }
    if (tid < 72)
      __builtin_amdgcn_global_load_lds(
          (const __attribute__((address_space(1))) void*)(WS + cursW[9]),
          (__attribute__((address_space(3))) void*)&L[C2_WOFF +
                                                     (4608 + tid) * 8],
          16, 0, 0);
    cursW[9] += C2_WADV;
    __syncthreads();  // drain: acts + weights resident

    // ---- compute: pure LDS + MFMA (144 MFMA/wave/step) ----
#pragma unroll
    for (int ky = 0; ky < 3; ky++) {
#pragma unroll
      for (int kx = 0; kx < 3; kx++) {
        int t = ky * 3 + kx;
        int wb = (t * 4 + quad) * 65 + cw * 32 + ln;
        f16x8 Ah0 = *(const f16x8*)&L[C2_WOFF + wb * 8];
        f16x8 Ah1 = *(const f16x8*)&L[C2_WOFF + (wb + 16) * 8];
        f16x8 Al0 = *(const f16x8*)&L[C2_WOFF + (wb + 2340) * 8];
        f16x8 Al1 = *(const f16x8*)&L[C2_WOFF + (wb + 2356) * 8];
#pragma unroll
        for (int s = 0; s < 4; s++) {
          int owl = (s & 1) * 16 + ln;
          int r = 4 * rw + 2 * (s >> 1) + ky;
          int abase = (quad * 17 + r) * 65;
          int uoff = (kx == 1) ? (33 + owl) : (owl + (kx == 2));
          f16x8 Bh = *(const f16x8*)&L[(abase + uoff) * 8];
          acc[0][s] = __builtin_amdgcn_mfma_f32_16x16x32_f16(Al0, Bh, acc[0][s], 0, 0, 0);
          acc[0][s] = __builtin_amdgcn_mfma_f32_16x16x32_f16(Ah0, Bh, acc[0][s], 0, 0, 0);
          acc[1][s] = __builtin_amdgcn_mfma_f32_16x16x32_f16(Al1, Bh, acc[1][s], 0, 0, 0);
          acc[1][s] = __builtin_amdgcn_mfma_f32_16x16x32_f16(Ah1, Bh, acc[1][s], 0, 0, 0);
        }
      }
    }
  }
  // epilogue: full sums for this co-half; bias+relu here
#pragma unroll
  for (int cs = 0; cs < 2; cs++)
#pragma unroll
    for (int s = 0; s < 4; s++) {
      int oh = oh0 + 2 * rw + (s >> 1);
      int ow = (s & 1) * 16 + ln;
#pragma unroll
      for (int r2 = 0; r2 < 4; r2++) {
        int co = cohalf * 64 + cw * 32 + cs * 16 + quad * 4 + r2;
        h2[((b * 128 + co) * 32 + oh) * 32 + ow] = fmaxf(acc[cs][s][r2] + b2[co], 0.f);
      }
    }
}

// ---------- pool(4x4 mean) + proj(1x1,128->64); grid 128 (b x quarter) ------
__global__ __launch_bounds__(256) void k_poolproj(const float* __restrict__ h2,
                                                  const float* __restrict__ wpT,
                                                  const float* __restrict__ pb,
                                                  float* __restrict__ z_e_out,
                                                  float* __restrict__ lossacc) {
  __shared__ float hp[128][16];
  __shared__ float Ws[128][64];
  int bx = blockIdx.x, tid = threadIdx.x;
  int b = bx >> 2, quarter = bx & 3;
  if (bx == 0 && tid == 0) lossacc[0] = 0.f;
  for (int i = tid; i < 8192; i += 256) Ws[i >> 6][i & 63] = wpT[i];
  for (int i = tid; i < 2048; i += 256) {
    int ci = i >> 4, pl = i & 15;
    int pi = quarter * 16 + pl;
    int bi = pi >> 3, bj = pi & 7;
    const float* src = &h2[((b * 128 + ci) * 32 + bi * 4) * 32 + bj * 4];
    float4 r0 = *(const float4*)src;
    float4 r1 = *(const float4*)(src + 32);
    float4 r2 = *(const float4*)(src + 64);
    float4 r3 = *(const float4*)(src + 96);
    float s = r0.x + r0.y + r0.z + r0.w + r1.x + r1.y + r1.z + r1.w +
              r2.x + r2.y + r2.z + r2.w + r3.x + r3.y + r3.z + r3.w;
    hp[ci][pl] = s * 0.0625f;
  }
  __syncthreads();
  int d = tid >> 2, s0 = (tid & 3) * 4;
  float4 acc = make_float4(0.f, 0.f, 0.f, 0.f);
  for (int k = 0; k < 128; k++) {
    float a = Ws[k][d];
    float4 h = *(float4*)&hp[k][s0];
    acc.x = fmaf(a, h.x, acc.x);
    acc.y = fmaf(a, h.y, acc.y);
    acc.z = fmaf(a, h.z, acc.z);
    acc.w = fmaf(a, h.w, acc.w);
  }
  float bv = pb[d];
  float4 r4 = make_float4(acc.x + bv, acc.y + bv, acc.z + bv, acc.w + bv);
  *(float4*)&z_e_out[(b * 64 + d) * 64 + quarter * 16 + s0] = r4;
}

// ---------- VQ argmin + loss + dproj; grid 2048 x 256 (4 waves) -------------
__global__ __launch_bounds__(256) void k_vqdproj(const float* __restrict__ z_e,
                                                 const float* __restrict__ cbT,
                                                 const float* __restrict__ cb,
                                                 const float* __restrict__ wdT,
                                                 const float* __restrict__ db,
                                                 float* __restrict__ idx_f,
                                                 _Float16* __restrict__ Yh,
                                                 _Float16* __restrict__ Yl,
                                                 float* __restrict__ loss_acc) {
  __shared__ float zs[64];
  __shared__ float zqv[64];
  __shared__ double wbst[4];
  __shared__ int wbi[4];
  int n = blockIdx.x, tid = threadIdx.x;
  int b = n >> 6, pi = n & 63;
  if (tid < 64) zs[tid] = z_e[(b * 64 + tid) * 64 + pi];
  if (n == 0 && tid < 64) {  // zero tail page for shifted reads in k_dec
    Yh[YTAIL + tid] = (_Float16)0.f;
    Yh[YTAIL + 64 + tid] = (_Float16)0.f;
    Yl[YTAIL + tid] = (_Float16)0.f;
    Yl[YTAIL + 64 + tid] = (_Float16)0.f;
  }
  __syncthreads();
  int w = tid >> 6, lane = tid & 63;
  double best = 1e300;
  int bi = 0;
#pragma unroll
  for (int j = 0; j < 2; j++) {
    int k = w * 128 + j * 64 + lane;
    double a0 = 0.0, a1 = 0.0, a2 = 0.0, a3 = 0.0;
#pragma unroll 4
    for (int d = 0; d < 64; d += 4) {
      double f0 = (double)zs[d] - (double)cbT[d * 512 + k];
      double f1 = (double)zs[d + 1] - (double)cbT[(d + 1) * 512 + k];
      double f2 = (double)zs[d + 2] - (double)cbT[(d + 2) * 512 + k];
      double f3 = (double)zs[d + 3] - (double)cbT[(d + 3) * 512 + k];
      a0 = fma(f0, f0, a0);
      a1 = fma(f1, f1, a1);
      a2 = fma(f2, f2, a2);
      a3 = fma(f3, f3, a3);
    }
    double acc = (a0 + a1) + (a2 + a3);
    if (acc < best) { best = acc; bi = k; }
  }
  for (int m = 1; m < 64; m <<= 1) {
    double ob = __shfl_xor(best, m, 64);
    int oi = __shfl_xor(bi, m, 64);
    if (ob < best || (ob == best && oi < bi)) { best = ob; bi = oi; }
  }
  if (lane == 0) { wbst[w] = best; wbi[w] = bi; }
  __syncthreads();
  best = wbst[0];
  bi = wbi[0];
#pragma unroll
  for (int q = 1; q < 4; q++) {
    double ob = wbst[q];
    int oi = wbi[q];
    if (ob < best || (ob == best && oi < bi)) { best = ob; bi = oi; }
  }
  if (tid < 64) {  // wave 0: loss + zq staging
    float zq_l = cb[bi * 64 + tid];
    float e = zq_l - zs[tid];
    float sq = e * e;
    for (int m = 1; m < 64; m <<= 1) sq += __shfl_xor(sq, m, 64);
    if (tid == 0) {
      idx_f[n] = (float)bi;
      atomicAdd(loss_acc, sq);
    }
    zqv[tid] = zq_l;
  }
  __syncthreads();
  if (tid < 128) {  // dproj: one co per thread
    float a = db[tid];
#pragma unroll 4
    for (int d = 0; d < 64; d++) a = fmaf(wdT[d * 128 + tid], zqv[d], a);
    float y = fmaxf(a, 0.f);
    _Float16 h = (_Float16)y;
    Yh[n * 128 + tid] = h;
    Yl[n * 128 + tid] = (_Float16)(y - (float)h);
  }
}

// ---------- dec: f16-split MFMA, G[pq][n][co] = A_pq * Yshift ----------
__global__ __launch_bounds__(256) void k_dec(const _Float16* __restrict__ Yh,
                                             const _Float16* __restrict__ Yl,
                                             const _Float16* __restrict__ Ah,
                                             const _Float16* __restrict__ Al,
                                             float* __restrict__ G) {
  int bxx = blockIdx.x;
  int pq = bxx >> 6, n_t = bxx & 63;
  int w = threadIdx.x >> 6, l = threadIdx.x & 63;
  int ln = l & 15, quad = l >> 4;
  int coW = w * 32;
  int nB = n_t * 32;
  int py = pq / 5, px = pq - py * 5;
  int dy = (py == 0) ? -1 : ((py == 4) ? 1 : 0);
  int dx = (px == 0) ? -1 : ((px == 4) ? 1 : 0);
  int src[2];
#pragma unroll
  for (int s = 0; s < 2; s++) {
    int n = nB + s * 16 + ln;
    int bb = n >> 6, s6 = n & 63;
    int sy = (s6 >> 3) + dy, sx = (s6 & 7) + dx;
    bool ok = ((unsigned)sy < 8u) && ((unsigned)sx < 8u);
    src[s] = ok ? ((bb * 64 + sy * 8 + sx) * 128) : YTAIL;
  }
  int kq = quad * 8;
  f32x4 acc[2][2] = {};
#pragma unroll 2
  for (int ci0 = 0; ci0 < 128; ci0 += 32) {
    const int wbase = (pq * 128 + coW + ln) * 128 + ci0 + kq;
    f16x8 Ah0 = *(const f16x8*)&Ah[wbase];
    f16x8 Al0 = *(const f16x8*)&Al[wbase];
    f16x8 Ah1 = *(const f16x8*)&Ah[wbase + 2048];
    f16x8 Al1 = *(const f16x8*)&Al[wbase + 2048];
    f16x8 Bh[2], Bl[2];
#pragma unroll
    for (int s = 0; s < 2; s++) {
      Bh[s] = *(const f16x8*)&Yh[src[s] + ci0 + kq];
      Bl[s] = *(const f16x8*)&Yl[src[s] + ci0 + kq];
    }
#pragma unroll
    for (int cs = 0; cs < 2; cs++) {
      f16x8 ah = cs ? Ah1 : Ah0;
      f16x8 al = cs ? Al1 : Al0;
#pragma unroll
      for (int s = 0; s < 2; s++) {
        acc[cs][s] = __builtin_amdgcn_mfma_f32_16x16x32_f16(al, Bh[s], acc[cs][s], 0, 0, 0);
        acc[cs][s] = __builtin_amdgcn_mfma_f32_16x16x32_f16(ah, Bl[s], acc[cs][s], 0, 0, 0);
        acc[cs][s] = __builtin_amdgcn_mfma_f32_16x16x32_f16(ah, Bh[s], acc[cs][s], 0, 0, 0);
      }
    }
  }
#pragma unroll
  for (int cs = 0; cs < 2; cs++)
#pragma unroll
    for (int s = 0; s < 2; s++) {
      int site = nB + s * 16 + ln;
      float4 g = make_float4(acc[cs][s][0], acc[cs][s][1], acc[cs][s][2], acc[cs][s][3]);
      *(float4*)&G[(pq * 2048 + site) * 128 + coW + cs * 16 + quad * 4] = g;
    }
}

// ---------- out: combine G per class, bias+relu, 1x1 conv to 3ch, splat ------
__global__ __launch_bounds__(256) void k_out(const float* __restrict__ G,
                                             const float* __restrict__ bc1,
                                             const float* __restrict__ w3,
                                             const float* __restrict__ b3,
                                             float* __restrict__ xhat,
                                             const float* __restrict__ loss_acc,
                                             float* __restrict__ out_loss) {
  __shared__ float Tb[9][128];
  __shared__ float part[9][3][8];
  __shared__ float vals[9][3];
  int bj = blockIdx.x, bi = blockIdx.y, b = blockIdx.z;
  int s = bi * 8 + bj;
  int n = b * 64 + s;
  int tid = threadIdx.x;
  if (bj == 0 && bi == 0 && b == 0 && tid == 0)
    out_loss[0] = loss_acc[0] * 1.25f / 131072.0f;
  int co = tid & 127, h = tid >> 7;
  const int rset[3][2] = {{0, 1}, {2, 2}, {3, 4}};
  const int rcnt[3] = {2, 1, 2};
  for (int cls = h; cls < 9; cls += 2) {
    int r = cls / 3, c = cls - r * 3;
    float sum = bc1[co];
    for (int iy = 0; iy < rcnt[r]; iy++) {
      int py = rset[r][iy];
      for (int ix = 0; ix < rcnt[c]; ix++) {
        int px = rset[c][ix];
        sum += G[((py * 5 + px) * 2048 + n) * 128 + co];
      }
    }
    Tb[cls][co] = fmaxf(sum, 0.f);
  }
  __syncthreads();
  if (tid < 216) {
    int cls = tid / 24, rem = tid - cls * 24;
    int cc = rem >> 3, seg = rem & 7;
    float ss = 0.f;
#pragma unroll
    for (int d = 0; d < 16; d++) ss = fmaf(w3[cc * 128 + seg * 16 + d], Tb[cls][seg * 16 + d], ss);
    part[cls][cc][seg] = ss;
  }
  __syncthreads();
  if (tid < 27) {
    int cls = tid / 3, cc = tid - cls * 3;
    float ss = b3[cc];
#pragma unroll
    for (int seg = 0; seg < 8; seg++) ss += part[cls][cc][seg];
    vals[cls][cc] = ss;
  }
  __syncthreads();
  for (int i = tid; i < 768; i += 256) {
    int cc = i >> 8, p = i & 255;
    int ry = p >> 4, rx = p & 15;
    int rcls = (ry == 0) ? 0 : ((ry == 15) ? 2 : 1);
    int ccls = (rx == 0) ? 0 : ((rx == 15) ? 2 : 1);
    xhat[((b * 3 + cc) * 128 + bi * 16 + ry) * 128 + bj * 16 + rx] =
        vals[rcls * 3 + ccls][cc];
  }
}

extern "C" void kernel_launch(void* const* d_in, const int* in_sizes, int n_in,
                              void* d_out, int out_size, void* d_ws, size_t ws_size,
                              hipStream_t stream) {
  const float* x   = (const float*)d_in[0];
  const float* w1  = (const float*)d_in[1];
  const float* b1  = (const float*)d_in[2];
  const float* w2  = (const float*)d_in[3];
  const float* b2  = (const float*)d_in[4];
  const float* wp  = (const float*)d_in[5];
  const float* pb  = (const float*)d_in[6];
  const float* cb  = (const float*)d_in[7];
  const float* wd  = (const float*)d_in[8];
  const float* db  = (const float*)d_in[9];
  const float* wc1 = (const float*)d_in[10];
  const float* bc1 = (const float*)d_in[11];
  const float* wc2 = (const float*)d_in[12];
  const float* bc2 = (const float*)d_in[13];
  float* out = (float*)d_out;
  float* ws  = (float*)d_ws;

  // workspace (float offsets):
  _Float16* h1h = (_Float16*)(ws);             // [0, 8388640) f16 plane (+tail)
  float* h2     = ws + 16777280;               // 4194304
  _Float16* WS  = (_Float16*)(ws + 20971584);  // 147456 fl (294912 f16)
  float* w1t    = ws + 21119040;               // 3456
  float* wpT    = ws + 21122496;               // 8192
  float* wdT    = ws + 21130688;               // 8192
  float* cbT    = ws + 21138880;               // 32768
  _Float16* Ahd = (_Float16*)(ws + 21171648);  // 204800 fl
  _Float16* Ald = (_Float16*)(ws + 21376448);  // 204800 fl -> end 21581248
  // overlays inside dead h1h region (valid after conv2):
  float* G       = ws;                         // [0, 6553600)
  _Float16* Yh   = (_Float16*)(ws + 6553600);  // 131136 fl (2049*128 f16)
  _Float16* Yl   = (_Float16*)(ws + 6684736);  // 131136 fl
  float* lossacc = ws + 6815872;               // 1

  float* o_xhat = out;
  float* o_idx  = out + 1572864;
  float* o_loss = out + 1574912;
  float* o_ze   = out + 1574913;

  static bool s_attr_done = false;
  if (!s_attr_done) {
    (void)hipFuncSetAttribute((const void*)k_conv2,
                              hipFuncAttributeMaxDynamicSharedMemorySize, C2_LDSB);
    s_attr_done = true;
  }

  k_prep<<<dim3(153), 256, 0, stream>>>(w2, w1, wp, wd, wc1, cb,
                                        w1t, wpT, wdT, cbT, Ahd, Ald, WS, h1h);
  k_conv1<<<dim3(4, 16, 32), 256, 0, stream>>>(x, w1t, b1, h1h);
  k_conv2<<<dim3(256), 512, C2_LDSB, stream>>>(h1h, WS, b2, h2);
  k_poolproj<<<dim3(128), 256, 0, stream>>>(h2, wpT, pb, o_ze, lossacc);
  k_vqdproj<<<dim3(2048), 256, 0, stream>>>(o_ze, cbT, cb, wdT, db, o_idx, Yh, Yl, lossacc);
  k_dec<<<dim3(1600), 256, 0, stream>>>(Yh, Yl, Ahd, Ald, G);
  k_out<<<dim3(8, 8, 32), 256, 0, stream>>>(G, bc1, wc2, bc2, o_xhat, lossacc, o_loss);
}

// Round 11
// 228.595 us; speedup vs baseline: 1.1040x; 1.0367x over previous
//
#include <hip/hip_runtime.h>
#include <math.h>

// ---------------------------------------------------------------------------
// VQVAE forward. v19: G eliminated. k_dec now accumulates the per-CLASS sum
// (k_out's Tb) directly in the MFMA accumulator: block = (cls(9) x n_t(64)),
// loops its class's 1/2/4 pq taps into one acc (same MFMA count, zero extra
// regs), adds bc1 + relu, writes Tb[9][2048][128] (9.4 MB vs G's 26.2 MB).
// k_out drops its G-sum phase and reads Tb rows. ~52 MB dec<->out round-trip
// becomes ~19 MB. conv2 keeps v18's fat-step all-LDS form (8 rows/block,
// 145.6 KB LDS) -- its drain-amortization ladder is at LDS capacity.
// ---------------------------------------------------------------------------

typedef _Float16 f16x8 __attribute__((ext_vector_type(8)));
typedef float f32x4 __attribute__((ext_vector_type(4)));

#define H1N 16777216        // elements in h1 plane; zero tail after
#define YTAIL (2048 * 128)  // zero page in Yh/Yl for OOB shifts

// ---------- prep: A-agg (0..127), W-layout (128..143), cbT (144..151), misc -
__global__ __launch_bounds__(256) void k_prep(const float* __restrict__ w2,
                                              const float* __restrict__ w1,
                                              const float* __restrict__ wp,
                                              const float* __restrict__ wd,
                                              const float* __restrict__ wd1,
                                              const float* __restrict__ cb,
                                              float* __restrict__ w1t,
                                              float* __restrict__ wpT,
                                              float* __restrict__ wdT,
                                              float* __restrict__ cbT,
                                              _Float16* __restrict__ Ah,
                                              _Float16* __restrict__ Al,
                                              _Float16* __restrict__ WS,
                                              _Float16* __restrict__ h1h) {
  int bx = blockIdx.x, tid = threadIdx.x;
  if (bx < 128) {  // ---- A aggregation, block = co, lanes = ci (writes coalesced)
    __shared__ float wrow[1152];
    int co = bx;
    for (int i = tid; i < 1152; i += 256) wrow[i] = wd1[co * 1152 + i];
    __syncthreads();
    if (tid < 128) {
      int ci = tid;
      float w[9];
#pragma unroll
      for (int t = 0; t < 9; t++) w[t] = wrow[ci * 9 + t];
      float rx[3][5];
#pragma unroll
      for (int ky = 0; ky < 3; ky++) {
        float a0 = w[ky * 3 + 0], a1 = w[ky * 3 + 1], a2 = w[ky * 3 + 2];
        rx[ky][0] = a0; rx[ky][1] = a1 + a2; rx[ky][2] = a0 + a1 + a2;
        rx[ky][3] = a0 + a1; rx[ky][4] = a2;
      }
#pragma unroll
      for (int px = 0; px < 5; px++) {
        float s0 = rx[0][px], s1 = rx[1][px], s2 = rx[2][px];
        float ry[5];
        ry[0] = s0; ry[1] = s1 + s2; ry[2] = s0 + s1 + s2; ry[3] = s0 + s1; ry[4] = s2;
#pragma unroll
        for (int py = 0; py < 5; py++) {
          int pq = py * 5 + px;
          float v = ry[py];
          _Float16 h = (_Float16)v;
          int o = (pq * 128 + co) * 128 + ci;
          Ah[o] = h;
          Al[o] = (_Float16)(v - (float)h);
        }
      }
    }
    return;
  }
  if (bx < 144) {  // ---- W layout for conv2 staging: [pl][tap][ci8g][co]x8
    __shared__ float wst[9216];
    int co0 = (bx - 128) * 8;
    for (int i = tid; i < 9216; i += 256) wst[i] = w2[co0 * 1152 + i];
    __syncthreads();
    for (int i = tid; i < 9216; i += 256) {
      int co = i / 1152, r = i - co * 1152;
      int tap = r >> 7, ci = r & 127;
      float v = wst[co * 1152 + ci * 9 + tap];
      _Float16 h = (_Float16)v;
      int og = ((tap * 16 + (ci >> 3)) * 128 + co0 + co) * 8 + (ci & 7);
      WS[og] = h;                                   // pl = 0 (high)
      WS[og + 147456] = (_Float16)(v - (float)h);   // pl = 1 (low); 9*16*128*8
    }
    return;
  }
  if (bx < 152) {  // ---- cbT tile transpose (64 k x 64 d), padded LDS
    __shared__ float cbs[64 * 65];
    int k0 = (bx - 144) * 64;
    for (int i = tid; i < 4096; i += 256) {
      int k = i >> 6, d = i & 63;
      cbs[k * 65 + d] = cb[(k0 + k) * 64 + d];
    }
    __syncthreads();
    for (int i = tid; i < 4096; i += 256) {
      int d = i >> 6, k = i & 63;
      cbT[d * 512 + k0 + k] = cbs[k * 65 + d];
    }
    return;
  }
  // ---- misc small transposes + h1 zero tail (writes lane-contiguous)
  for (int i = tid; i < 3456; i += 256) {  // w1t[t][co] = w1[co][t]
    int co = i & 127, t = i >> 7;
    w1t[t * 128 + co] = w1[co * 27 + t];
  }
  for (int i = tid; i < 8192; i += 256) {  // wpT[k][d] = wp[d][k]
    int d = i & 63, k = i >> 6;
    wpT[k * 64 + d] = wp[d * 128 + k];
  }
  for (int i = tid; i < 8192; i += 256) {  // wdT[d][co] = wd[co][d]
    int co = i & 127, d = i >> 7;
    wdT[d * 128 + co] = wd[co * 64 + d];
  }
  if (tid < 64) h1h[H1N + tid] = (_Float16)0.f;
}

// ---------- conv1: (32,3,128,128) -> h1 f16 [g][b][oh][ow][8ci] -------------
__global__ __launch_bounds__(256) void k_conv1(const float* __restrict__ x,
                                               const float* __restrict__ w1t,
                                               const float* __restrict__ b1,
                                               _Float16* __restrict__ h1h) {
  __shared__ float E[3][9][68];
  __shared__ float O[3][9][68];
  int co_t = blockIdx.x, oh_t = blockIdx.y, b = blockIdx.z;
  int oh0 = oh_t * 4;
  int tid = threadIdx.x;
  int wv = __builtin_amdgcn_readfirstlane(tid >> 6);
  int l = tid & 63;
  int coB = co_t * 32 + wv * 8;

  for (int idx = tid; idx < 1728; idx += 256) {
    int p = idx & 63, r = idx >> 6;
    int ci = r / 9, lr = r - ci * 9;
    int ih = 2 * oh0 - 1 + lr;
    float2 v = make_float2(0.f, 0.f);
    if ((unsigned)ih < 128u)
      v = *(const float2*)&x[((b * 3 + ci) * 128 + ih) * 128 + 2 * p];
    E[ci][lr][p] = v.x;
    O[ci][lr][p + 1] = v.y;
  }
  if (tid < 27) {
    int ci = tid / 9, lr = tid - ci * 9;
    O[ci][lr][0] = 0.f;
  }
  __syncthreads();

  int ohl = l >> 4, ow0 = (l & 15) * 4;
  int oh = oh0 + ohl;
  float4 acc[8];
#pragma unroll
  for (int q = 0; q < 8; q++) {
    float bv = b1[coB + q];
    acc[q] = make_float4(bv, bv, bv, bv);
  }
#pragma unroll
  for (int ci = 0; ci < 3; ci++) {
#pragma unroll
    for (int ky = 0; ky < 3; ky++) {
      int lr = 2 * ohl + ky;
      float4 ev = *(float4*)&E[ci][lr][ow0];
      float4 od = *(float4*)&O[ci][lr][ow0];
      float o4 = O[ci][lr][ow0 + 4];
      const float* wr = w1t + (ci * 9 + ky * 3) * 128 + coB;
#pragma unroll
      for (int q = 0; q < 8; q++) {
        float wa = wr[q], wb = wr[128 + q], wc = wr[256 + q];
        acc[q].x = fmaf(wa, od.x, acc[q].x);
        acc[q].x = fmaf(wb, ev.x, acc[q].x);
        acc[q].x = fmaf(wc, od.y, acc[q].x);
        acc[q].y = fmaf(wa, od.y, acc[q].y);
        acc[q].y = fmaf(wb, ev.y, acc[q].y);
        acc[q].y = fmaf(wc, od.z, acc[q].y);
        acc[q].z = fmaf(wa, od.z, acc[q].z);
        acc[q].z = fmaf(wb, ev.z, acc[q].z);
        acc[q].z = fmaf(wc, od.w, acc[q].z);
        acc[q].w = fmaf(wa, od.w, acc[q].w);
        acc[q].w = fmaf(wb, ev.w, acc[q].w);
        acc[q].w = fmaf(wc, o4,   acc[q].w);
      }
    }
  }
  int g = coB >> 3;
  int pbase = ((g * 32 + b) * 64 + oh) * 64;
#pragma unroll
  for (int oi = 0; oi < 4; oi++) {
    f16x8 hv;
#pragma unroll
    for (int q = 0; q < 8; q++)
      hv[q] = (_Float16)fmaxf(((const float*)&acc[q])[oi], 0.f);
    *(f16x8*)&h1h[(pbase + ow0 + oi) * 8] = hv;
  }
}

// ---------- conv2: fat-step all-LDS compute; 8 output rows per block --------
// grid 256 = (b(32) x ohq(4) x cohalf(2)); block 512 = 8 waves. wave w:
// cw = w&1 (co-group of 32 within the 64-co half), rw = w>>1 (row-pair:
// rows oh0+2rw, oh0+2rw+1). acc[cs 2][s 4], s = (row-in-pair<<1)|col-half.
// LDS: acts [0, 70720 B): chunk (g*17+r)*65 + (ph?33+u:u), g=ci8(4),
//      r=input row(17: ih=2*oh0-1+r).
//      weights [70720, 145600 B): chunk ((pl*9+t)*4+quad)*65 + co_in_64.
// Per step: stage acts+weights (gload_lds) -> barrier(drain) -> compute
// (pure ds_read+MFMA) -> barrier. 4 steps, 145.6 KB LDS, 1 block/CU.
#define C2_ACHUNK 4420                          // 4*17*65
#define C2_WCHUNK 4680
#define C2_WOFF (C2_ACHUNK * 8)                 // f16 offset of weight region
#define C2_LDSB ((C2_ACHUNK + C2_WCHUNK) * 16)  // 145600 bytes
#define C2_STEP 4194304                         // h1 advance per +32ci step
#define C2_WADV 4096                            // WS f16 advance per step

__global__ __launch_bounds__(512, 2) void k_conv2(const _Float16* __restrict__ h1h,
                                                  const _Float16* __restrict__ WS,
                                                  const float* __restrict__ b2,
                                                  float* __restrict__ h2) {
  extern __shared__ _Float16 L[];
  int bx = blockIdx.x;
  int cohalf = bx & 1;
  int bq = bx >> 1;
  int b = bq >> 2, ohq = bq & 3;
  int oh0 = ohq * 8;
  int tid = threadIdx.x;
  int w = tid >> 6, l = tid & 63;
  int cw = w & 1, rw = w >> 1;
  int ln = l & 15, quad = l >> 4;

  // ---- act staging descriptors: 9 chunks/thread (tail tid<324) ----
  int cursA[9];
  int advA[9];
#pragma unroll
  for (int k = 0; k < 9; k++) {
    int c = (k < 8) ? (tid + k * 512) : (4096 + tid);
    if (c < C2_ACHUNK) {
      int q = c / 65, rem = c - q * 65;
      int ph = rem >= 33;
      int u = ph ? rem - 33 : rem;
      int r = q % 17, g = q / 17;
      int iw = ph ? 2 * u : 2 * u - 1;
      int ih = 2 * oh0 - 1 + r;
      bool ok = (ih >= 0) && (iw >= 0) && (iw < 64);
      cursA[k] = ok ? ((g * 32 + b) * 64 + ih) * 512 + iw * 8 : H1N;
      advA[k] = ok ? C2_STEP : 0;
    } else {
      cursA[k] = H1N;
      advA[k] = 0;
    }
  }
  // ---- weight staging descriptors: 10 chunks/thread (tail tid<72) ----
  int cursW[10];
#pragma unroll
  for (int k = 0; k < 10; k++) {
    int c = (k < 9) ? (tid + k * 512) : (4608 + tid);
    if (c < C2_WCHUNK) {
      int q65 = c / 65, u = c - q65 * 65;
      if (u > 63) u = 63;  // pad slot: stage harmless duplicate
      int pl = q65 >= 36;
      int r36 = q65 - pl * 36;
      int t = r36 >> 2, ci8 = r36 & 3;
      cursW[k] = ((pl * 9 + t) * 16 + ci8) * 1024 + (cohalf * 64 + u) * 8;
    } else {
      cursW[k] = 0;
    }
  }

  f32x4 acc[2][4] = {};  // [cs][s]
  for (int step = 0; step < 4; step++) {
    if (step) __syncthreads();  // prior compute done reading L
    // ---- stage acts(step) ----
#pragma unroll
    for (int k = 0; k < 8; k++) {
      __builtin_amdgcn_global_load_lds(
          (const __attribute__((address_space(1))) void*)(h1h + cursA[k]),
          (__attribute__((address_space(3))) void*)&L[(tid + k * 512) * 8],
          16, 0, 0);
      cursA[k] += advA[k];
    }
    if (tid < 324)
      __builtin_amdgcn_global_load_lds(
          (const __attribute__((address_space(1))) void*)(h1h + cursA[8]),
          (__attribute__((address_space(3))) void*)&L[(4096 + tid) * 8],
          16, 0, 0);
    cursA[8] += advA[8];
    // ---- stage weights(step) ----
#pragma unroll
    for (int k = 0; k < 9; k++) {
      __builtin_amdgcn_global_load_lds(
          (const __attribute__((address_space(1))) void*)(WS + cursW[k]),
          (__attribute__((address_space(3))) void*)&L[C2_WOFF +
                                                     (tid + k * 512) * 8],
          16, 0, 0);
      cursW[k] += C2_WADV;
    }
    if (tid < 72)
      __builtin_amdgcn_global_load_lds(
          (const __attribute__((address_space(1))) void*)(WS + cursW[9]),
          (__attribute__((address_space(3))) void*)&L[C2_WOFF +
                                                     (4608 + tid) * 8],
          16, 0, 0);
    cursW[9] += C2_WADV;
    __syncthreads();  // drain: acts + weights resident

    // ---- compute: pure LDS + MFMA (144 MFMA/wave/step) ----
#pragma unroll
    for (int ky = 0; ky < 3; ky++) {
#pragma unroll
      for (int kx = 0; kx < 3; kx++) {
        int t = ky * 3 + kx;
        int wb = (t * 4 + quad) * 65 + cw * 32 + ln;
        f16x8 Ah0 = *(const f16x8*)&L[C2_WOFF + wb * 8];
        f16x8 Ah1 = *(const f16x8*)&L[C2_WOFF + (wb + 16) * 8];
        f16x8 Al0 = *(const f16x8*)&L[C2_WOFF + (wb + 2340) * 8];
        f16x8 Al1 = *(const f16x8*)&L[C2_WOFF + (wb + 2356) * 8];
#pragma unroll
        for (int s = 0; s < 4; s++) {
          int owl = (s & 1) * 16 + ln;
          int r = 4 * rw + 2 * (s >> 1) + ky;
          int abase = (quad * 17 + r) * 65;
          int uoff = (kx == 1) ? (33 + owl) : (owl + (kx == 2));
          f16x8 Bh = *(const f16x8*)&L[(abase + uoff) * 8];
          acc[0][s] = __builtin_amdgcn_mfma_f32_16x16x32_f16(Al0, Bh, acc[0][s], 0, 0, 0);
          acc[0][s] = __builtin_amdgcn_mfma_f32_16x16x32_f16(Ah0, Bh, acc[0][s], 0, 0, 0);
          acc[1][s] = __builtin_amdgcn_mfma_f32_16x16x32_f16(Al1, Bh, acc[1][s], 0, 0, 0);
          acc[1][s] = __builtin_amdgcn_mfma_f32_16x16x32_f16(Ah1, Bh, acc[1][s], 0, 0, 0);
        }
      }
    }
  }
  // epilogue: full sums for this co-half; bias+relu here
#pragma unroll
  for (int cs = 0; cs < 2; cs++)
#pragma unroll
    for (int s = 0; s < 4; s++) {
      int oh = oh0 + 2 * rw + (s >> 1);
      int ow = (s & 1) * 16 + ln;
#pragma unroll
      for (int r2 = 0; r2 < 4; r2++) {
        int co = cohalf * 64 + cw * 32 + cs * 16 + quad * 4 + r2;
        h2[((b * 128 + co) * 32 + oh) * 32 + ow] = fmaxf(acc[cs][s][r2] + b2[co], 0.f);
      }
    }
}

// ---------- pool(4x4 mean) + proj(1x1,128->64); grid 128 (b x quarter) ------
__global__ __launch_bounds__(256) void k_poolproj(const float* __restrict__ h2,
                                                  const float* __restrict__ wpT,
                                                  const float* __restrict__ pb,
                                                  float* __restrict__ z_e_out,
                                                  float* __restrict__ lossacc) {
  __shared__ float hp[128][16];
  __shared__ float Ws[128][64];
  int bx = blockIdx.x, tid = threadIdx.x;
  int b = bx >> 2, quarter = bx & 3;
  if (bx == 0 && tid == 0) lossacc[0] = 0.f;
  for (int i = tid; i < 8192; i += 256) Ws[i >> 6][i & 63] = wpT[i];
  for (int i = tid; i < 2048; i += 256) {
    int ci = i >> 4, pl = i & 15;
    int pi = quarter * 16 + pl;
    int bi = pi >> 3, bj = pi & 7;
    const float* src = &h2[((b * 128 + ci) * 32 + bi * 4) * 32 + bj * 4];
    float4 r0 = *(const float4*)src;
    float4 r1 = *(const float4*)(src + 32);
    float4 r2 = *(const float4*)(src + 64);
    float4 r3 = *(const float4*)(src + 96);
    float s = r0.x + r0.y + r0.z + r0.w + r1.x + r1.y + r1.z + r1.w +
              r2.x + r2.y + r2.z + r2.w + r3.x + r3.y + r3.z + r3.w;
    hp[ci][pl] = s * 0.0625f;
  }
  __syncthreads();
  int d = tid >> 2, s0 = (tid & 3) * 4;
  float4 acc = make_float4(0.f, 0.f, 0.f, 0.f);
  for (int k = 0; k < 128; k++) {
    float a = Ws[k][d];
    float4 h = *(float4*)&hp[k][s0];
    acc.x = fmaf(a, h.x, acc.x);
    acc.y = fmaf(a, h.y, acc.y);
    acc.z = fmaf(a, h.z, acc.z);
    acc.w = fmaf(a, h.w, acc.w);
  }
  float bv = pb[d];
  float4 r4 = make_float4(acc.x + bv, acc.y + bv, acc.z + bv, acc.w + bv);
  *(float4*)&z_e_out[(b * 64 + d) * 64 + quarter * 16 + s0] = r4;
}

// ---------- VQ argmin + loss + dproj; grid 2048 x 256 (4 waves) -------------
__global__ __launch_bounds__(256) void k_vqdproj(const float* __restrict__ z_e,
                                                 const float* __restrict__ cbT,
                                                 const float* __restrict__ cb,
                                                 const float* __restrict__ wdT,
                                                 const float* __restrict__ db,
                                                 float* __restrict__ idx_f,
                                                 _Float16* __restrict__ Yh,
                                                 _Float16* __restrict__ Yl,
                                                 float* __restrict__ loss_acc) {
  __shared__ float zs[64];
  __shared__ float zqv[64];
  __shared__ double wbst[4];
  __shared__ int wbi[4];
  int n = blockIdx.x, tid = threadIdx.x;
  int b = n >> 6, pi = n & 63;
  if (tid < 64) zs[tid] = z_e[(b * 64 + tid) * 64 + pi];
  if (n == 0 && tid < 64) {  // zero tail page for shifted reads in k_dec
    Yh[YTAIL + tid] = (_Float16)0.f;
    Yh[YTAIL + 64 + tid] = (_Float16)0.f;
    Yl[YTAIL + tid] = (_Float16)0.f;
    Yl[YTAIL + 64 + tid] = (_Float16)0.f;
  }
  __syncthreads();
  int w = tid >> 6, lane = tid & 63;
  double best = 1e300;
  int bi = 0;
#pragma unroll
  for (int j = 0; j < 2; j++) {
    int k = w * 128 + j * 64 + lane;
    double a0 = 0.0, a1 = 0.0, a2 = 0.0, a3 = 0.0;
#pragma unroll 4
    for (int d = 0; d < 64; d += 4) {
      double f0 = (double)zs[d] - (double)cbT[d * 512 + k];
      double f1 = (double)zs[d + 1] - (double)cbT[(d + 1) * 512 + k];
      double f2 = (double)zs[d + 2] - (double)cbT[(d + 2) * 512 + k];
      double f3 = (double)zs[d + 3] - (double)cbT[(d + 3) * 512 + k];
      a0 = fma(f0, f0, a0);
      a1 = fma(f1, f1, a1);
      a2 = fma(f2, f2, a2);
      a3 = fma(f3, f3, a3);
    }
    double acc = (a0 + a1) + (a2 + a3);
    if (acc < best) { best = acc; bi = k; }
  }
  for (int m = 1; m < 64; m <<= 1) {
    double ob = __shfl_xor(best, m, 64);
    int oi = __shfl_xor(bi, m, 64);
    if (ob < best || (ob == best && oi < bi)) { best = ob; bi = oi; }
  }
  if (lane == 0) { wbst[w] = best; wbi[w] = bi; }
  __syncthreads();
  best = wbst[0];
  bi = wbi[0];
#pragma unroll
  for (int q = 1; q < 4; q++) {
    double ob = wbst[q];
    int oi = wbi[q];
    if (ob < best || (ob == best && oi < bi)) { best = ob; bi = oi; }
  }
  if (tid < 64) {  // wave 0: loss + zq staging
    float zq_l = cb[bi * 64 + tid];
    float e = zq_l - zs[tid];
    float sq = e * e;
    for (int m = 1; m < 64; m <<= 1) sq += __shfl_xor(sq, m, 64);
    if (tid == 0) {
      idx_f[n] = (float)bi;
      atomicAdd(loss_acc, sq);
    }
    zqv[tid] = zq_l;
  }
  __syncthreads();
  if (tid < 128) {  // dproj: one co per thread
    float a = db[tid];
#pragma unroll 4
    for (int d = 0; d < 64; d++) a = fmaf(wdT[d * 128 + tid], zqv[d], a);
    float y = fmaxf(a, 0.f);
    _Float16 h = (_Float16)y;
    Yh[n * 128 + tid] = h;
    Yl[n * 128 + tid] = (_Float16)(y - (float)h);
  }
}

// ---------- dec: per-CLASS accumulated f16-split MFMA -> Tb[9][2048][128] ---
// grid 576 = (cls(9) x n_t(64)); block 256 = 4 waves (wave w: co w*32..+31).
// Tb[cls][n][co] = relu(bc1[co] + sum_{pq in cls} A_pq . Y[shift_pq(n)]);
// the pq-sum rides in the MFMA accumulator (same MFMA count as per-pq dec,
// zero extra registers). G never materializes (26.2 -> 9.4 MB).
__global__ __launch_bounds__(256) void k_dec(const _Float16* __restrict__ Yh,
                                             const _Float16* __restrict__ Yl,
                                             const _Float16* __restrict__ Ah,
                                             const _Float16* __restrict__ Al,
                                             const float* __restrict__ bc1,
                                             float* __restrict__ Tb) {
  int bxx = blockIdx.x;
  int cls = bxx >> 6, n_t = bxx & 63;
  int rc = cls / 3, c3 = cls - rc * 3;
  const int rset[3][2] = {{0, 1}, {2, 2}, {3, 4}};
  const int rcnt[3] = {2, 1, 2};
  int w = threadIdx.x >> 6, l = threadIdx.x & 63;
  int ln = l & 15, quad = l >> 4;
  int coW = w * 32;
  int nB = n_t * 32;
  int kq = quad * 8;
  f32x4 acc[2][2] = {};
  for (int iy = 0; iy < rcnt[rc]; iy++) {
    int py = rset[rc][iy];
    int dy = (py == 0) ? -1 : ((py == 4) ? 1 : 0);
    for (int ix = 0; ix < rcnt[c3]; ix++) {
      int px = rset[c3][ix];
      int dx = (px == 0) ? -1 : ((px == 4) ? 1 : 0);
      int pq = py * 5 + px;
      int src[2];
#pragma unroll
      for (int s = 0; s < 2; s++) {
        int n = nB + s * 16 + ln;
        int bb = n >> 6, s6 = n & 63;
        int sy = (s6 >> 3) + dy, sx = (s6 & 7) + dx;
        bool ok = ((unsigned)sy < 8u) && ((unsigned)sx < 8u);
        src[s] = ok ? ((bb * 64 + sy * 8 + sx) * 128) : YTAIL;
      }
#pragma unroll 2
      for (int ci0 = 0; ci0 < 128; ci0 += 32) {
        const int wbase = (pq * 128 + coW + ln) * 128 + ci0 + kq;
        f16x8 Ah0 = *(const f16x8*)&Ah[wbase];
        f16x8 Al0 = *(const f16x8*)&Al[wbase];
        f16x8 Ah1 = *(const f16x8*)&Ah[wbase + 2048];
        f16x8 Al1 = *(const f16x8*)&Al[wbase + 2048];
        f16x8 Bh[2], Bl[2];
#pragma unroll
        for (int s = 0; s < 2; s++) {
          Bh[s] = *(const f16x8*)&Yh[src[s] + ci0 + kq];
          Bl[s] = *(const f16x8*)&Yl[src[s] + ci0 + kq];
        }
#pragma unroll
        for (int cs = 0; cs < 2; cs++) {
          f16x8 ah = cs ? Ah1 : Ah0;
          f16x8 al = cs ? Al1 : Al0;
#pragma unroll
          for (int s = 0; s < 2; s++) {
            acc[cs][s] = __builtin_amdgcn_mfma_f32_16x16x32_f16(al, Bh[s], acc[cs][s], 0, 0, 0);
            acc[cs][s] = __builtin_amdgcn_mfma_f32_16x16x32_f16(ah, Bl[s], acc[cs][s], 0, 0, 0);
            acc[cs][s] = __builtin_amdgcn_mfma_f32_16x16x32_f16(ah, Bh[s], acc[cs][s], 0, 0, 0);
          }
        }
      }
    }
  }
  // epilogue: bc1 + relu, write Tb[cls][site][co]
#pragma unroll
  for (int cs = 0; cs < 2; cs++)
#pragma unroll
    for (int s = 0; s < 2; s++) {
      int site = nB + s * 16 + ln;
      int co0 = coW + cs * 16 + quad * 4;
      float4 bv = *(const float4*)&bc1[co0];
      float4 g = make_float4(fmaxf(acc[cs][s][0] + bv.x, 0.f),
                             fmaxf(acc[cs][s][1] + bv.y, 0.f),
                             fmaxf(acc[cs][s][2] + bv.z, 0.f),
                             fmaxf(acc[cs][s][3] + bv.w, 0.f));
      *(float4*)&Tb[(cls * 2048 + site) * 128 + co0] = g;
    }
}

// ---------- out: read Tb, 1x1 conv to 3ch, splat ----------------------------
__global__ __launch_bounds__(256) void k_out(const float* __restrict__ TbG,
                                             const float* __restrict__ w3,
                                             const float* __restrict__ b3,
                                             float* __restrict__ xhat,
                                             const float* __restrict__ loss_acc,
                                             float* __restrict__ out_loss) {
  __shared__ float Tb[9][128];
  __shared__ float part[9][3][8];
  __shared__ float vals[9][3];
  int bj = blockIdx.x, bi = blockIdx.y, b = blockIdx.z;
  int s = bi * 8 + bj;
  int n = b * 64 + s;
  int tid = threadIdx.x;
  if (bj == 0 && bi == 0 && b == 0 && tid == 0)
    out_loss[0] = loss_acc[0] * 1.25f / 131072.0f;
  for (int i = tid; i < 1152; i += 256) {
    int cls = i >> 7, co = i & 127;
    Tb[cls][co] = TbG[(cls * 2048 + n) * 128 + co];
  }
  __syncthreads();
  if (tid < 216) {
    int cls = tid / 24, rem = tid - cls * 24;
    int cc = rem >> 3, seg = rem & 7;
    float ss = 0.f;
#pragma unroll
    for (int d = 0; d < 16; d++) ss = fmaf(w3[cc * 128 + seg * 16 + d], Tb[cls][seg * 16 + d], ss);
    part[cls][cc][seg] = ss;
  }
  __syncthreads();
  if (tid < 27) {
    int cls = tid / 3, cc = tid - cls * 3;
    float ss = b3[cc];
#pragma unroll
    for (int seg = 0; seg < 8; seg++) ss += part[cls][cc][seg];
    vals[cls][cc] = ss;
  }
  __syncthreads();
  for (int i = tid; i < 768; i += 256) {
    int cc = i >> 8, p = i & 255;
    int ry = p >> 4, rx = p & 15;
    int rcls = (ry == 0) ? 0 : ((ry == 15) ? 2 : 1);
    int ccls = (rx == 0) ? 0 : ((rx == 15) ? 2 : 1);
    xhat[((b * 3 + cc) * 128 + bi * 16 + ry) * 128 + bj * 16 + rx] =
        vals[rcls * 3 + ccls][cc];
  }
}

extern "C" void kernel_launch(void* const* d_in, const int* in_sizes, int n_in,
                              void* d_out, int out_size, void* d_ws, size_t ws_size,
                              hipStream_t stream) {
  const float* x   = (const float*)d_in[0];
  const float* w1  = (const float*)d_in[1];
  const float* b1  = (const float*)d_in[2];
  const float* w2  = (const float*)d_in[3];
  const float* b2  = (const float*)d_in[4];
  const float* wp  = (const float*)d_in[5];
  const float* pb  = (const float*)d_in[6];
  const float* cb  = (const float*)d_in[7];
  const float* wd  = (const float*)d_in[8];
  const float* db  = (const float*)d_in[9];
  const float* wc1 = (const float*)d_in[10];
  const float* bc1 = (const float*)d_in[11];
  const float* wc2 = (const float*)d_in[12];
  const float* bc2 = (const float*)d_in[13];
  float* out = (float*)d_out;
  float* ws  = (float*)d_ws;

  // workspace (float offsets):
  _Float16* h1h = (_Float16*)(ws);             // [0, 8388640) f16 plane (+tail)
  float* h2     = ws + 16777280;               // 4194304
  _Float16* WS  = (_Float16*)(ws + 20971584);  // 147456 fl (294912 f16)
  float* w1t    = ws + 21119040;               // 3456
  float* wpT    = ws + 21122496;               // 8192
  float* wdT    = ws + 21130688;               // 8192
  float* cbT    = ws + 21138880;               // 32768
  _Float16* Ahd = (_Float16*)(ws + 21171648);  // 204800 fl
  _Float16* Ald = (_Float16*)(ws + 21376448);  // 204800 fl -> end 21581248
  // overlays inside dead h1h region (valid after conv2):
  float* Tb      = ws;                         // [0, 2359296) 9*2048*128
  _Float16* Yh   = (_Float16*)(ws + 6553600);  // 131136 fl (2049*128 f16)
  _Float16* Yl   = (_Float16*)(ws + 6684736);  // 131136 fl
  float* lossacc = ws + 6815872;               // 1

  float* o_xhat = out;
  float* o_idx  = out + 1572864;
  float* o_loss = out + 1574912;
  float* o_ze   = out + 1574913;

  static bool s_attr_done = false;
  if (!s_attr_done) {
    (void)hipFuncSetAttribute((const void*)k_conv2,
                              hipFuncAttributeMaxDynamicSharedMemorySize, C2_LDSB);
    s_attr_done = true;
  }

  k_prep<<<dim3(153), 256, 0, stream>>>(w2, w1, wp, wd, wc1, cb,
                                        w1t, wpT, wdT, cbT, Ahd, Ald, WS, h1h);
  k_conv1<<<dim3(4, 16, 32), 256, 0, stream>>>(x, w1t, b1, h1h);
  k_conv2<<<dim3(256), 512, C2_LDSB, stream>>>(h1h, WS, b2, h2);
  k_poolproj<<<dim3(128), 256, 0, stream>>>(h2, wpT, pb, o_ze, lossacc);
  k_vqdproj<<<dim3(2048), 256, 0, stream>>>(o_ze, cbT, cb, wdT, db, o_idx, Yh, Yl, lossacc);
  k_dec<<<dim3(576), 256, 0, stream>>>(Yh, Yl, Ahd, Ald, bc1, Tb);
  k_out<<<dim3(8, 8, 32), 256, 0, stream>>>(Tb, wc2, bc2, o_xhat, lossacc, o_loss);
}

// Round 12
// 225.762 us; speedup vs baseline: 1.1178x; 1.0125x over previous
//
#include <hip/hip_runtime.h>
#include <math.h>

// ---------------------------------------------------------------------------
// VQVAE forward. v20: h2 eliminated. conv2's epilogue now fuses the 4x4
// mean-pool: relu(acc+b2) staged to dead LDS (h2s 64 KB), one barrier, then
// 1024 pool cells reduced per block IN v19's EXACT row-major add order
// (pooled values bit-identical -> z_e bit-identical) and written as pooled
// h2p (1 MB vs h2's 16.8 MB). poolproj becomes proj-only. Saves ~19 MB of
// conv2<->poolproj round-trip. All other kernels unchanged from v19.
// ---------------------------------------------------------------------------

typedef _Float16 f16x8 __attribute__((ext_vector_type(8)));
typedef float f32x4 __attribute__((ext_vector_type(4)));

#define H1N 16777216        // elements in h1 plane; zero tail after
#define YTAIL (2048 * 128)  // zero page in Yh/Yl for OOB shifts

// ---------- prep: A-agg (0..127), W-layout (128..143), cbT (144..151), misc -
__global__ __launch_bounds__(256) void k_prep(const float* __restrict__ w2,
                                              const float* __restrict__ w1,
                                              const float* __restrict__ wp,
                                              const float* __restrict__ wd,
                                              const float* __restrict__ wd1,
                                              const float* __restrict__ cb,
                                              float* __restrict__ w1t,
                                              float* __restrict__ wpT,
                                              float* __restrict__ wdT,
                                              float* __restrict__ cbT,
                                              _Float16* __restrict__ Ah,
                                              _Float16* __restrict__ Al,
                                              _Float16* __restrict__ WS,
                                              _Float16* __restrict__ h1h) {
  int bx = blockIdx.x, tid = threadIdx.x;
  if (bx < 128) {  // ---- A aggregation, block = co, lanes = ci (writes coalesced)
    __shared__ float wrow[1152];
    int co = bx;
    for (int i = tid; i < 1152; i += 256) wrow[i] = wd1[co * 1152 + i];
    __syncthreads();
    if (tid < 128) {
      int ci = tid;
      float w[9];
#pragma unroll
      for (int t = 0; t < 9; t++) w[t] = wrow[ci * 9 + t];
      float rx[3][5];
#pragma unroll
      for (int ky = 0; ky < 3; ky++) {
        float a0 = w[ky * 3 + 0], a1 = w[ky * 3 + 1], a2 = w[ky * 3 + 2];
        rx[ky][0] = a0; rx[ky][1] = a1 + a2; rx[ky][2] = a0 + a1 + a2;
        rx[ky][3] = a0 + a1; rx[ky][4] = a2;
      }
#pragma unroll
      for (int px = 0; px < 5; px++) {
        float s0 = rx[0][px], s1 = rx[1][px], s2 = rx[2][px];
        float ry[5];
        ry[0] = s0; ry[1] = s1 + s2; ry[2] = s0 + s1 + s2; ry[3] = s0 + s1; ry[4] = s2;
#pragma unroll
        for (int py = 0; py < 5; py++) {
          int pq = py * 5 + px;
          float v = ry[py];
          _Float16 h = (_Float16)v;
          int o = (pq * 128 + co) * 128 + ci;
          Ah[o] = h;
          Al[o] = (_Float16)(v - (float)h);
        }
      }
    }
    return;
  }
  if (bx < 144) {  // ---- W layout for conv2 staging: [pl][tap][ci8g][co]x8
    __shared__ float wst[9216];
    int co0 = (bx - 128) * 8;
    for (int i = tid; i < 9216; i += 256) wst[i] = w2[co0 * 1152 + i];
    __syncthreads();
    for (int i = tid; i < 9216; i += 256) {
      int co = i / 1152, r = i - co * 1152;
      int tap = r >> 7, ci = r & 127;
      float v = wst[co * 1152 + ci * 9 + tap];
      _Float16 h = (_Float16)v;
      int og = ((tap * 16 + (ci >> 3)) * 128 + co0 + co) * 8 + (ci & 7);
      WS[og] = h;                                   // pl = 0 (high)
      WS[og + 147456] = (_Float16)(v - (float)h);   // pl = 1 (low); 9*16*128*8
    }
    return;
  }
  if (bx < 152) {  // ---- cbT tile transpose (64 k x 64 d), padded LDS
    __shared__ float cbs[64 * 65];
    int k0 = (bx - 144) * 64;
    for (int i = tid; i < 4096; i += 256) {
      int k = i >> 6, d = i & 63;
      cbs[k * 65 + d] = cb[(k0 + k) * 64 + d];
    }
    __syncthreads();
    for (int i = tid; i < 4096; i += 256) {
      int d = i >> 6, k = i & 63;
      cbT[d * 512 + k0 + k] = cbs[k * 65 + d];
    }
    return;
  }
  // ---- misc small transposes + h1 zero tail (writes lane-contiguous)
  for (int i = tid; i < 3456; i += 256) {  // w1t[t][co] = w1[co][t]
    int co = i & 127, t = i >> 7;
    w1t[t * 128 + co] = w1[co * 27 + t];
  }
  for (int i = tid; i < 8192; i += 256) {  // wpT[k][d] = wp[d][k]
    int d = i & 63, k = i >> 6;
    wpT[k * 64 + d] = wp[d * 128 + k];
  }
  for (int i = tid; i < 8192; i += 256) {  // wdT[d][co] = wd[co][d]
    int co = i & 127, d = i >> 7;
    wdT[d * 128 + co] = wd[co * 64 + d];
  }
  if (tid < 64) h1h[H1N + tid] = (_Float16)0.f;
}

// ---------- conv1: (32,3,128,128) -> h1 f16 [g][b][oh][ow][8ci] -------------
__global__ __launch_bounds__(256) void k_conv1(const float* __restrict__ x,
                                               const float* __restrict__ w1t,
                                               const float* __restrict__ b1,
                                               _Float16* __restrict__ h1h) {
  __shared__ float E[3][9][68];
  __shared__ float O[3][9][68];
  int co_t = blockIdx.x, oh_t = blockIdx.y, b = blockIdx.z;
  int oh0 = oh_t * 4;
  int tid = threadIdx.x;
  int wv = __builtin_amdgcn_readfirstlane(tid >> 6);
  int l = tid & 63;
  int coB = co_t * 32 + wv * 8;

  for (int idx = tid; idx < 1728; idx += 256) {
    int p = idx & 63, r = idx >> 6;
    int ci = r / 9, lr = r - ci * 9;
    int ih = 2 * oh0 - 1 + lr;
    float2 v = make_float2(0.f, 0.f);
    if ((unsigned)ih < 128u)
      v = *(const float2*)&x[((b * 3 + ci) * 128 + ih) * 128 + 2 * p];
    E[ci][lr][p] = v.x;
    O[ci][lr][p + 1] = v.y;
  }
  if (tid < 27) {
    int ci = tid / 9, lr = tid - ci * 9;
    O[ci][lr][0] = 0.f;
  }
  __syncthreads();

  int ohl = l >> 4, ow0 = (l & 15) * 4;
  int oh = oh0 + ohl;
  float4 acc[8];
#pragma unroll
  for (int q = 0; q < 8; q++) {
    float bv = b1[coB + q];
    acc[q] = make_float4(bv, bv, bv, bv);
  }
#pragma unroll
  for (int ci = 0; ci < 3; ci++) {
#pragma unroll
    for (int ky = 0; ky < 3; ky++) {
      int lr = 2 * ohl + ky;
      float4 ev = *(float4*)&E[ci][lr][ow0];
      float4 od = *(float4*)&O[ci][lr][ow0];
      float o4 = O[ci][lr][ow0 + 4];
      const float* wr = w1t + (ci * 9 + ky * 3) * 128 + coB;
#pragma unroll
      for (int q = 0; q < 8; q++) {
        float wa = wr[q], wb = wr[128 + q], wc = wr[256 + q];
        acc[q].x = fmaf(wa, od.x, acc[q].x);
        acc[q].x = fmaf(wb, ev.x, acc[q].x);
        acc[q].x = fmaf(wc, od.y, acc[q].x);
        acc[q].y = fmaf(wa, od.y, acc[q].y);
        acc[q].y = fmaf(wb, ev.y, acc[q].y);
        acc[q].y = fmaf(wc, od.z, acc[q].y);
        acc[q].z = fmaf(wa, od.z, acc[q].z);
        acc[q].z = fmaf(wb, ev.z, acc[q].z);
        acc[q].z = fmaf(wc, od.w, acc[q].z);
        acc[q].w = fmaf(wa, od.w, acc[q].w);
        acc[q].w = fmaf(wb, ev.w, acc[q].w);
        acc[q].w = fmaf(wc, o4,   acc[q].w);
      }
    }
  }
  int g = coB >> 3;
  int pbase = ((g * 32 + b) * 64 + oh) * 64;
#pragma unroll
  for (int oi = 0; oi < 4; oi++) {
    f16x8 hv;
#pragma unroll
    for (int q = 0; q < 8; q++)
      hv[q] = (_Float16)fmaxf(((const float*)&acc[q])[oi], 0.f);
    *(f16x8*)&h1h[(pbase + ow0 + oi) * 8] = hv;
  }
}

// ---------- conv2: fat-step all-LDS compute + fused 4x4 mean-pool ----------
// grid 256 = (b(32) x ohq(4) x cohalf(2)); block 512 = 8 waves. wave w:
// cw = w&1 (co-group of 32 within the 64-co half), rw = w>>1 (row-pair:
// rows oh0+2rw, oh0+2rw+1). acc[cs 2][s 4], s = (row-in-pair<<1)|col-half.
// LDS: acts [0, 70720 B): chunk (g*17+r)*65 + (ph?33+u:u), g=ci8(4),
//      r=input row(17: ih=2*oh0-1+r).
//      weights [70720, 145600 B): chunk ((pl*9+t)*4+quad)*65 + co_in_64.
// Per step: stage acts+weights (gload_lds) -> barrier(drain) -> compute
// (pure ds_read+MFMA) -> barrier. 4 steps, 145.6 KB LDS.
// Epilogue: relu(acc+b2) -> LDS h2s[64co][8r][32c] (reuses dead act region)
// -> 4x4 mean in v19 poolproj's exact row-major add order -> pooled h2p
// [b][128co][8pr][8pc] (1 MB). h2 (16.8 MB) never materializes.
#define C2_ACHUNK 4420                          // 4*17*65
#define C2_WCHUNK 4680
#define C2_WOFF (C2_ACHUNK * 8)                 // f16 offset of weight region
#define C2_LDSB ((C2_ACHUNK + C2_WCHUNK) * 16)  // 145600 bytes
#define C2_STEP 4194304                         // h1 advance per +32ci step
#define C2_WADV 4096                            // WS f16 advance per step

__global__ __launch_bounds__(512, 2) void k_conv2(const _Float16* __restrict__ h1h,
                                                  const _Float16* __restrict__ WS,
                                                  const float* __restrict__ b2,
                                                  float* __restrict__ h2p) {
  extern __shared__ _Float16 L[];
  int bx = blockIdx.x;
  int cohalf = bx & 1;
  int bq = bx >> 1;
  int b = bq >> 2, ohq = bq & 3;
  int oh0 = ohq * 8;
  int tid = threadIdx.x;
  int w = tid >> 6, l = tid & 63;
  int cw = w & 1, rw = w >> 1;
  int ln = l & 15, quad = l >> 4;

  // ---- act staging descriptors: 9 chunks/thread (tail tid<324) ----
  int cursA[9];
  int advA[9];
#pragma unroll
  for (int k = 0; k < 9; k++) {
    int c = (k < 8) ? (tid + k * 512) : (4096 + tid);
    if (c < C2_ACHUNK) {
      int q = c / 65, rem = c - q * 65;
      int ph = rem >= 33;
      int u = ph ? rem - 33 : rem;
      int r = q % 17, g = q / 17;
      int iw = ph ? 2 * u : 2 * u - 1;
      int ih = 2 * oh0 - 1 + r;
      bool ok = (ih >= 0) && (iw >= 0) && (iw < 64);
      cursA[k] = ok ? ((g * 32 + b) * 64 + ih) * 512 + iw * 8 : H1N;
      advA[k] = ok ? C2_STEP : 0;
    } else {
      cursA[k] = H1N;
      advA[k] = 0;
    }
  }
  // ---- weight staging descriptors: 10 chunks/thread (tail tid<72) ----
  int cursW[10];
#pragma unroll
  for (int k = 0; k < 10; k++) {
    int c = (k < 9) ? (tid + k * 512) : (4608 + tid);
    if (c < C2_WCHUNK) {
      int q65 = c / 65, u = c - q65 * 65;
      if (u > 63) u = 63;  // pad slot: stage harmless duplicate
      int pl = q65 >= 36;
      int r36 = q65 - pl * 36;
      int t = r36 >> 2, ci8 = r36 & 3;
      cursW[k] = ((pl * 9 + t) * 16 + ci8) * 1024 + (cohalf * 64 + u) * 8;
    } else {
      cursW[k] = 0;
    }
  }

  f32x4 acc[2][4] = {};  // [cs][s]
  for (int step = 0; step < 4; step++) {
    if (step) __syncthreads();  // prior compute done reading L
    // ---- stage acts(step) ----
#pragma unroll
    for (int k = 0; k < 8; k++) {
      __builtin_amdgcn_global_load_lds(
          (const __attribute__((address_space(1))) void*)(h1h + cursA[k]),
          (__attribute__((address_space(3))) void*)&L[(tid + k * 512) * 8],
          16, 0, 0);
      cursA[k] += advA[k];
    }
    if (tid < 324)
      __builtin_amdgcn_global_load_lds(
          (const __attribute__((address_space(1))) void*)(h1h + cursA[8]),
          (__attribute__((address_space(3))) void*)&L[(4096 + tid) * 8],
          16, 0, 0);
    cursA[8] += advA[8];
    // ---- stage weights(step) ----
#pragma unroll
    for (int k = 0; k < 9; k++) {
      __builtin_amdgcn_global_load_lds(
          (const __attribute__((address_space(1))) void*)(WS + cursW[k]),
          (__attribute__((address_space(3))) void*)&L[C2_WOFF +
                                                     (tid + k * 512) * 8],
          16, 0, 0);
      cursW[k] += C2_WADV;
    }
    if (tid < 72)
      __builtin_amdgcn_global_load_lds(
          (const __attribute__((address_space(1))) void*)(WS + cursW[9]),
          (__attribute__((address_space(3))) void*)&L[C2_WOFF +
                                                     (4608 + tid) * 8],
          16, 0, 0);
    cursW[9] += C2_WADV;
    __syncthreads();  // drain: acts + weights resident

    // ---- compute: pure LDS + MFMA (144 MFMA/wave/step) ----
#pragma unroll
    for (int ky = 0; ky < 3; ky++) {
#pragma unroll
      for (int kx = 0; kx < 3; kx++) {
        int t = ky * 3 + kx;
        int wb = (t * 4 + quad) * 65 + cw * 32 + ln;
        f16x8 Ah0 = *(const f16x8*)&L[C2_WOFF + wb * 8];
        f16x8 Ah1 = *(const f16x8*)&L[C2_WOFF + (wb + 16) * 8];
        f16x8 Al0 = *(const f16x8*)&L[C2_WOFF + (wb + 2340) * 8];
        f16x8 Al1 = *(const f16x8*)&L[C2_WOFF + (wb + 2356) * 8];
#pragma unroll
        for (int s = 0; s < 4; s++) {
          int owl = (s & 1) * 16 + ln;
          int r = 4 * rw + 2 * (s >> 1) + ky;
          int abase = (quad * 17 + r) * 65;
          int uoff = (kx == 1) ? (33 + owl) : (owl + (kx == 2));
          f16x8 Bh = *(const f16x8*)&L[(abase + uoff) * 8];
          acc[0][s] = __builtin_amdgcn_mfma_f32_16x16x32_f16(Al0, Bh, acc[0][s], 0, 0, 0);
          acc[0][s] = __builtin_amdgcn_mfma_f32_16x16x32_f16(Ah0, Bh, acc[0][s], 0, 0, 0);
          acc[1][s] = __builtin_amdgcn_mfma_f32_16x16x32_f16(Al1, Bh, acc[1][s], 0, 0, 0);
          acc[1][s] = __builtin_amdgcn_mfma_f32_16x16x32_f16(Ah1, Bh, acc[1][s], 0, 0, 0);
        }
      }
    }
  }
  // ---- epilogue: fused 4x4 mean-pool ----
  __syncthreads();  // all waves done reading L; reuse act region as h2s
  float* h2s = (float*)L;  // [64co][8row][32col] = 65536 B < 70720 B
#pragma unroll
  for (int cs = 0; cs < 2; cs++)
#pragma unroll
    for (int s = 0; s < 4; s++) {
      int row = 2 * rw + (s >> 1);
      int col = (s & 1) * 16 + ln;
#pragma unroll
      for (int r2 = 0; r2 < 4; r2++) {
        int co64 = cw * 32 + cs * 16 + quad * 4 + r2;
        int co = cohalf * 64 + co64;
        h2s[(co64 * 8 + row) * 32 + col] = fmaxf(acc[cs][s][r2] + b2[co], 0.f);
      }
    }
  __syncthreads();
  // 1024 pool cells (64co x 2pr x 8pc); v19 poolproj's exact add order
  for (int c = tid; c < 1024; c += 512) {
    int co64 = c >> 4, rem = c & 15;
    int pr = rem >> 3, pc = rem & 7;
    const float* base = &h2s[(co64 * 8 + pr * 4) * 32 + pc * 4];
    float s = 0.f;
#pragma unroll
    for (int rr = 0; rr < 4; rr++) {
      s += base[rr * 32 + 0];
      s += base[rr * 32 + 1];
      s += base[rr * 32 + 2];
      s += base[rr * 32 + 3];
    }
    h2p[((b * 128 + cohalf * 64 + co64) * 8 + (2 * ohq + pr)) * 8 + pc] =
        s * 0.0625f;
  }
}

// ---------- proj(1x1,128->64) on pooled input; grid 128 (b x quarter) -------
__global__ __launch_bounds__(256) void k_poolproj(const float* __restrict__ h2p,
                                                  const float* __restrict__ wpT,
                                                  const float* __restrict__ pb,
                                                  float* __restrict__ z_e_out,
                                                  float* __restrict__ lossacc) {
  __shared__ float hp[128][16];
  __shared__ float Ws[128][64];
  int bx = blockIdx.x, tid = threadIdx.x;
  int b = bx >> 2, quarter = bx & 3;
  if (bx == 0 && tid == 0) lossacc[0] = 0.f;
  for (int i = tid; i < 8192; i += 256) Ws[i >> 6][i & 63] = wpT[i];
  for (int i = tid; i < 2048; i += 256) {
    int ci = i >> 4, pl = i & 15;
    hp[ci][pl] = h2p[(b * 128 + ci) * 64 + quarter * 16 + pl];
  }
  __syncthreads();
  int d = tid >> 2, s0 = (tid & 3) * 4;
  float4 acc = make_float4(0.f, 0.f, 0.f, 0.f);
  for (int k = 0; k < 128; k++) {
    float a = Ws[k][d];
    float4 h = *(float4*)&hp[k][s0];
    acc.x = fmaf(a, h.x, acc.x);
    acc.y = fmaf(a, h.y, acc.y);
    acc.z = fmaf(a, h.z, acc.z);
    acc.w = fmaf(a, h.w, acc.w);
  }
  float bv = pb[d];
  float4 r4 = make_float4(acc.x + bv, acc.y + bv, acc.z + bv, acc.w + bv);
  *(float4*)&z_e_out[(b * 64 + d) * 64 + quarter * 16 + s0] = r4;
}

// ---------- VQ argmin + loss + dproj; grid 2048 x 256 (4 waves) -------------
__global__ __launch_bounds__(256) void k_vqdproj(const float* __restrict__ z_e,
                                                 const float* __restrict__ cbT,
                                                 const float* __restrict__ cb,
                                                 const float* __restrict__ wdT,
                                                 const float* __restrict__ db,
                                                 float* __restrict__ idx_f,
                                                 _Float16* __restrict__ Yh,
                                                 _Float16* __restrict__ Yl,
                                                 float* __restrict__ loss_acc) {
  __shared__ float zs[64];
  __shared__ float zqv[64];
  __shared__ double wbst[4];
  __shared__ int wbi[4];
  int n = blockIdx.x, tid = threadIdx.x;
  int b = n >> 6, pi = n & 63;
  if (tid < 64) zs[tid] = z_e[(b * 64 + tid) * 64 + pi];
  if (n == 0 && tid < 64) {  // zero tail page for shifted reads in k_dec
    Yh[YTAIL + tid] = (_Float16)0.f;
    Yh[YTAIL + 64 + tid] = (_Float16)0.f;
    Yl[YTAIL + tid] = (_Float16)0.f;
    Yl[YTAIL + 64 + tid] = (_Float16)0.f;
  }
  __syncthreads();
  int w = tid >> 6, lane = tid & 63;
  double best = 1e300;
  int bi = 0;
#pragma unroll
  for (int j = 0; j < 2; j++) {
    int k = w * 128 + j * 64 + lane;
    double a0 = 0.0, a1 = 0.0, a2 = 0.0, a3 = 0.0;
#pragma unroll 4
    for (int d = 0; d < 64; d += 4) {
      double f0 = (double)zs[d] - (double)cbT[d * 512 + k];
      double f1 = (double)zs[d + 1] - (double)cbT[(d + 1) * 512 + k];
      double f2 = (double)zs[d + 2] - (double)cbT[(d + 2) * 512 + k];
      double f3 = (double)zs[d + 3] - (double)cbT[(d + 3) * 512 + k];
      a0 = fma(f0, f0, a0);
      a1 = fma(f1, f1, a1);
      a2 = fma(f2, f2, a2);
      a3 = fma(f3, f3, a3);
    }
    double acc = (a0 + a1) + (a2 + a3);
    if (acc < best) { best = acc; bi = k; }
  }
  for (int m = 1; m < 64; m <<= 1) {
    double ob = __shfl_xor(best, m, 64);
    int oi = __shfl_xor(bi, m, 64);
    if (ob < best || (ob == best && oi < bi)) { best = ob; bi = oi; }
  }
  if (lane == 0) { wbst[w] = best; wbi[w] = bi; }
  __syncthreads();
  best = wbst[0];
  bi = wbi[0];
#pragma unroll
  for (int q = 1; q < 4; q++) {
    double ob = wbst[q];
    int oi = wbi[q];
    if (ob < best || (ob == best && oi < bi)) { best = ob; bi = oi; }
  }
  if (tid < 64) {  // wave 0: loss + zq staging
    float zq_l = cb[bi * 64 + tid];
    float e = zq_l - zs[tid];
    float sq = e * e;
    for (int m = 1; m < 64; m <<= 1) sq += __shfl_xor(sq, m, 64);
    if (tid == 0) {
      idx_f[n] = (float)bi;
      atomicAdd(loss_acc, sq);
    }
    zqv[tid] = zq_l;
  }
  __syncthreads();
  if (tid < 128) {  // dproj: one co per thread
    float a = db[tid];
#pragma unroll 4
    for (int d = 0; d < 64; d++) a = fmaf(wdT[d * 128 + tid], zqv[d], a);
    float y = fmaxf(a, 0.f);
    _Float16 h = (_Float16)y;
    Yh[n * 128 + tid] = h;
    Yl[n * 128 + tid] = (_Float16)(y - (float)h);
  }
}

// ---------- dec: per-CLASS accumulated f16-split MFMA -> Tb[9][2048][128] ---
__global__ __launch_bounds__(256) void k_dec(const _Float16* __restrict__ Yh,
                                             const _Float16* __restrict__ Yl,
                                             const _Float16* __restrict__ Ah,
                                             const _Float16* __restrict__ Al,
                                             const float* __restrict__ bc1,
                                             float* __restrict__ Tb) {
  int bxx = blockIdx.x;
  int cls = bxx >> 6, n_t = bxx & 63;
  int rc = cls / 3, c3 = cls - rc * 3;
  const int rset[3][2] = {{0, 1}, {2, 2}, {3, 4}};
  const int rcnt[3] = {2, 1, 2};
  int w = threadIdx.x >> 6, l = threadIdx.x & 63;
  int ln = l & 15, quad = l >> 4;
  int coW = w * 32;
  int nB = n_t * 32;
  int kq = quad * 8;
  f32x4 acc[2][2] = {};
  for (int iy = 0; iy < rcnt[rc]; iy++) {
    int py = rset[rc][iy];
    int dy = (py == 0) ? -1 : ((py == 4) ? 1 : 0);
    for (int ix = 0; ix < rcnt[c3]; ix++) {
      int px = rset[c3][ix];
      int dx = (px == 0) ? -1 : ((px == 4) ? 1 : 0);
      int pq = py * 5 + px;
      int src[2];
#pragma unroll
      for (int s = 0; s < 2; s++) {
        int n = nB + s * 16 + ln;
        int bb = n >> 6, s6 = n & 63;
        int sy = (s6 >> 3) + dy, sx = (s6 & 7) + dx;
        bool ok = ((unsigned)sy < 8u) && ((unsigned)sx < 8u);
        src[s] = ok ? ((bb * 64 + sy * 8 + sx) * 128) : YTAIL;
      }
#pragma unroll 2
      for (int ci0 = 0; ci0 < 128; ci0 += 32) {
        const int wbase = (pq * 128 + coW + ln) * 128 + ci0 + kq;
        f16x8 Ah0 = *(const f16x8*)&Ah[wbase];
        f16x8 Al0 = *(const f16x8*)&Al[wbase];
        f16x8 Ah1 = *(const f16x8*)&Ah[wbase + 2048];
        f16x8 Al1 = *(const f16x8*)&Al[wbase + 2048];
        f16x8 Bh[2], Bl[2];
#pragma unroll
        for (int s = 0; s < 2; s++) {
          Bh[s] = *(const f16x8*)&Yh[src[s] + ci0 + kq];
          Bl[s] = *(const f16x8*)&Yl[src[s] + ci0 + kq];
        }
#pragma unroll
        for (int cs = 0; cs < 2; cs++) {
          f16x8 ah = cs ? Ah1 : Ah0;
          f16x8 al = cs ? Al1 : Al0;
#pragma unroll
          for (int s = 0; s < 2; s++) {
            acc[cs][s] = __builtin_amdgcn_mfma_f32_16x16x32_f16(al, Bh[s], acc[cs][s], 0, 0, 0);
            acc[cs][s] = __builtin_amdgcn_mfma_f32_16x16x32_f16(ah, Bl[s], acc[cs][s], 0, 0, 0);
            acc[cs][s] = __builtin_amdgcn_mfma_f32_16x16x32_f16(ah, Bh[s], acc[cs][s], 0, 0, 0);
          }
        }
      }
    }
  }
  // epilogue: bc1 + relu, write Tb[cls][site][co]
#pragma unroll
  for (int cs = 0; cs < 2; cs++)
#pragma unroll
    for (int s = 0; s < 2; s++) {
      int site = nB + s * 16 + ln;
      int co0 = coW + cs * 16 + quad * 4;
      float4 bv = *(const float4*)&bc1[co0];
      float4 g = make_float4(fmaxf(acc[cs][s][0] + bv.x, 0.f),
                             fmaxf(acc[cs][s][1] + bv.y, 0.f),
                             fmaxf(acc[cs][s][2] + bv.z, 0.f),
                             fmaxf(acc[cs][s][3] + bv.w, 0.f));
      *(float4*)&Tb[(cls * 2048 + site) * 128 + co0] = g;
    }
}

// ---------- out: read Tb, 1x1 conv to 3ch, splat ----------------------------
__global__ __launch_bounds__(256) void k_out(const float* __restrict__ TbG,
                                             const float* __restrict__ w3,
                                             const float* __restrict__ b3,
                                             float* __restrict__ xhat,
                                             const float* __restrict__ loss_acc,
                                             float* __restrict__ out_loss) {
  __shared__ float Tb[9][128];
  __shared__ float part[9][3][8];
  __shared__ float vals[9][3];
  int bj = blockIdx.x, bi = blockIdx.y, b = blockIdx.z;
  int s = bi * 8 + bj;
  int n = b * 64 + s;
  int tid = threadIdx.x;
  if (bj == 0 && bi == 0 && b == 0 && tid == 0)
    out_loss[0] = loss_acc[0] * 1.25f / 131072.0f;
  for (int i = tid; i < 1152; i += 256) {
    int cls = i >> 7, co = i & 127;
    Tb[cls][co] = TbG[(cls * 2048 + n) * 128 + co];
  }
  __syncthreads();
  if (tid < 216) {
    int cls = tid / 24, rem = tid - cls * 24;
    int cc = rem >> 3, seg = rem & 7;
    float ss = 0.f;
#pragma unroll
    for (int d = 0; d < 16; d++) ss = fmaf(w3[cc * 128 + seg * 16 + d], Tb[cls][seg * 16 + d], ss);
    part[cls][cc][seg] = ss;
  }
  __syncthreads();
  if (tid < 27) {
    int cls = tid / 3, cc = tid - cls * 3;
    float ss = b3[cc];
#pragma unroll
    for (int seg = 0; seg < 8; seg++) ss += part[cls][cc][seg];
    vals[cls][cc] = ss;
  }
  __syncthreads();
  for (int i = tid; i < 768; i += 256) {
    int cc = i >> 8, p = i & 255;
    int ry = p >> 4, rx = p & 15;
    int rcls = (ry == 0) ? 0 : ((ry == 15) ? 2 : 1);
    int ccls = (rx == 0) ? 0 : ((rx == 15) ? 2 : 1);
    xhat[((b * 3 + cc) * 128 + bi * 16 + ry) * 128 + bj * 16 + rx] =
        vals[rcls * 3 + ccls][cc];
  }
}

extern "C" void kernel_launch(void* const* d_in, const int* in_sizes, int n_in,
                              void* d_out, int out_size, void* d_ws, size_t ws_size,
                              hipStream_t stream) {
  const float* x   = (const float*)d_in[0];
  const float* w1  = (const float*)d_in[1];
  const float* b1  = (const float*)d_in[2];
  const float* w2  = (const float*)d_in[3];
  const float* b2  = (const float*)d_in[4];
  const float* wp  = (const float*)d_in[5];
  const float* pb  = (const float*)d_in[6];
  const float* cb  = (const float*)d_in[7];
  const float* wd  = (const float*)d_in[8];
  const float* db  = (const float*)d_in[9];
  const float* wc1 = (const float*)d_in[10];
  const float* bc1 = (const float*)d_in[11];
  const float* wc2 = (const float*)d_in[12];
  const float* bc2 = (const float*)d_in[13];
  float* out = (float*)d_out;
  float* ws  = (float*)d_ws;

  // workspace (float offsets):
  _Float16* h1h = (_Float16*)(ws);             // [0, 8388640) f16 plane (+tail)
  float* h2p    = ws + 16777280;               // 262144 (pooled)
  _Float16* WS  = (_Float16*)(ws + 20971584);  // 147456 fl (294912 f16)
  float* w1t    = ws + 21119040;               // 3456
  float* wpT    = ws + 21122496;               // 8192
  float* wdT    = ws + 21130688;               // 8192
  float* cbT    = ws + 21138880;               // 32768
  _Float16* Ahd = (_Float16*)(ws + 21171648);  // 204800 fl
  _Float16* Ald = (_Float16*)(ws + 21376448);  // 204800 fl -> end 21581248
  // overlays inside dead h1h region (valid after conv2):
  float* Tb      = ws;                         // [0, 2359296) 9*2048*128
  _Float16* Yh   = (_Float16*)(ws + 6553600);  // 131136 fl (2049*128 f16)
  _Float16* Yl   = (_Float16*)(ws + 6684736);  // 131136 fl
  float* lossacc = ws + 6815872;               // 1

  float* o_xhat = out;
  float* o_idx  = out + 1572864;
  float* o_loss = out + 1574912;
  float* o_ze   = out + 1574913;

  static bool s_attr_done = false;
  if (!s_attr_done) {
    (void)hipFuncSetAttribute((const void*)k_conv2,
                              hipFuncAttributeMaxDynamicSharedMemorySize, C2_LDSB);
    s_attr_done = true;
  }

  k_prep<<<dim3(153), 256, 0, stream>>>(w2, w1, wp, wd, wc1, cb,
                                        w1t, wpT, wdT, cbT, Ahd, Ald, WS, h1h);
  k_conv1<<<dim3(4, 16, 32), 256, 0, stream>>>(x, w1t, b1, h1h);
  k_conv2<<<dim3(256), 512, C2_LDSB, stream>>>(h1h, WS, b2, h2p);
  k_poolproj<<<dim3(128), 256, 0, stream>>>(h2p, wpT, pb, o_ze, lossacc);
  k_vqdproj<<<dim3(2048), 256, 0, stream>>>(o_ze, cbT, cb, wdT, db, o_idx, Yh, Yl, lossacc);
  k_dec<<<dim3(576), 256, 0, stream>>>(Yh, Yl, Ahd, Ald, bc1, Tb);
  k_out<<<dim3(8, 8, 32), 256, 0, stream>>>(Tb, wc2, bc2, o_xhat, lossacc, o_loss);
}